// Round 1
// baseline (3827.243 us; speedup 1.0000x reference)
//
#include <hip/hip_runtime.h>
#include <math.h>

constexpr int CC    = 64;          // channels
constexpr int NHEAD = 4;
constexpr int DH    = 16;          // head dim
constexpr int GG    = 8;           // window size
constexpr int H0    = 256;
constexpr int W0c   = 256;
constexpr int BB    = 2;
constexpr int LL    = H0 * W0c;                     // 65536
constexpr int NWIN  = BB * (H0 / GG) * (W0c / GG);  // 2048
constexpr int NT    = 128;                          // tokens per window (2*G*G)
constexpr int HIDN  = 256;                          // MLP hidden
constexpr int NBIA  = 31 * 15;                      // 465 relative-pos entries
constexpr long long MODSZ = (long long)BB * LL * CC; // 8388608 floats per modality

// ---------------------------------------------------------------------------
// Kernel P: dynamic position bias table (465 x 4) via tiny MLP
// ---------------------------------------------------------------------------
static __device__ __forceinline__ void ln4_relu(float* p, const float* g, const float* b) {
  float mu = 0.25f * (p[0] + p[1] + p[2] + p[3]);
  float d0 = p[0] - mu, d1 = p[1] - mu, d2 = p[2] - mu, d3 = p[3] - mu;
  float var = 0.25f * (d0 * d0 + d1 * d1 + d2 * d2 + d3 * d3);
  float rs = rsqrtf(var + 1e-5f);
  p[0] = fmaxf(d0 * rs * g[0] + b[0], 0.0f);
  p[1] = fmaxf(d1 * rs * g[1] + b[1], 0.0f);
  p[2] = fmaxf(d2 * rs * g[2] + b[2], 0.0f);
  p[3] = fmaxf(d3 * rs * g[3] + b[3], 0.0f);
}
static __device__ __forceinline__ void mm4(const float* a, const float* w, const float* b, float* o) {
  #pragma unroll
  for (int j = 0; j < 4; ++j) {
    float s = b[j];
    #pragma unroll
    for (int i = 0; i < 4; ++i) s += a[i] * w[i * 4 + j];
    o[j] = s;
  }
}

__global__ void pbias_kernel(const float* __restrict__ pp_w, const float* __restrict__ pp_b,
                             const float* __restrict__ ln1g, const float* __restrict__ ln1b,
                             const float* __restrict__ l1w,  const float* __restrict__ l1b,
                             const float* __restrict__ ln2g, const float* __restrict__ ln2b,
                             const float* __restrict__ l2w,  const float* __restrict__ l2b,
                             const float* __restrict__ ln3g, const float* __restrict__ ln3b,
                             const float* __restrict__ l3w,  const float* __restrict__ l3b,
                             float* __restrict__ p_table) {
  int r = blockIdx.x * blockDim.x + threadIdx.x;
  if (r >= NBIA) return;
  float bh = (float)(r / 15 - 15);   // 1-Gh .. Gh-1, Gh=16
  float bw = (float)(r % 15 - 7);    // 1-Gw .. Gw-1, Gw=8
  float a[4], t[4];
  #pragma unroll
  for (int j = 0; j < 4; ++j) a[j] = bh * pp_w[j] + bw * pp_w[4 + j] + pp_b[j];
  ln4_relu(a, ln1g, ln1b);
  mm4(a, l1w, l1b, t);
  ln4_relu(t, ln2g, ln2b);
  mm4(t, l2w, l2b, a);
  ln4_relu(a, ln3g, ln3b);
  mm4(a, l3w, l3b, t);
  #pragma unroll
  for (int j = 0; j < 4; ++j) p_table[r * 4 + j] = t[j];
}

// ---------------------------------------------------------------------------
// Kernel W: fused LN -> window gather -> QKV -> attention -> proj -> residual
// one block per window (2048 blocks), 256 threads = 4 waves
// ---------------------------------------------------------------------------
__launch_bounds__(256, 1)
__global__ void win_attn_kernel(const float* __restrict__ x, const float* __restrict__ y,
                                const float* __restrict__ n1g, const float* __restrict__ n1b,
                                const float* __restrict__ qkv_w, const float* __restrict__ qkv_b,
                                const float* __restrict__ proj_w, const float* __restrict__ proj_b,
                                const float* __restrict__ p_table, float* __restrict__ out) {
  __shared__ float tokL[NT][CC + 1];       // tokens; reused as attention output
  __shared__ float qkvL[3][NT][CC + 1];    // q (pre-scaled), k, v
  __shared__ float pT[NBIA * 5];           // bias table, stride 5 to spread banks

  const int tid  = threadIdx.x;
  const int lane = tid & 63;
  const int wv   = tid >> 6;

  const int widx = blockIdx.x;
  const int b  = widx >> 10;
  const int wl = widx & 1023;
  const int wh = wl >> 5, ww = wl & 31;

  // ---- token gather + LayerNorm(norm1): wave handles tokens wv, wv+4, ... ----
  for (int t = wv; t < NT; t += 4) {
    const int g = t & 63;
    const float* src = ((t & 64) ? y : x)
        + ((long long)b * LL + (long long)(wh * GG + (g >> 3)) * W0c + (ww * GG + (g & 7))) * CC;
    float v = src[lane];
    float s = v, s2 = v * v;
    #pragma unroll
    for (int o = 32; o; o >>= 1) { s += __shfl_xor(s, o); s2 += __shfl_xor(s2, o); }
    float mu  = s * (1.0f / 64.0f);
    float var = fmaxf(s2 * (1.0f / 64.0f) - mu * mu, 0.0f);
    float rs  = rsqrtf(var + 1e-5f);
    tokL[t][lane] = (v - mu) * rs * n1g[lane] + n1b[lane];
  }
  for (int i = tid; i < NBIA * 4; i += 256) pT[(i >> 2) * 5 + (i & 3)] = p_table[i];
  __syncthreads();

  // ---- QKV: wave computes 48 output channels for tokens (lane, lane+64) ----
  {
    const int c0 = __builtin_amdgcn_readfirstlane(wv * 48);
    float a0c[48], a1c[48];
    #pragma unroll
    for (int c = 0; c < 48; ++c) { float bb = qkv_b[c0 + c]; a0c[c] = bb; a1c[c] = bb; }
    const float* trA = &tokL[lane][0];
    const float* trB = &tokL[lane + 64][0];
    #pragma unroll 4
    for (int i = 0; i < CC; ++i) {
      float a0 = trA[i], a1 = trB[i];
      const float* wr = qkv_w + i * (3 * CC) + c0;
      #pragma unroll
      for (int c = 0; c < 48; ++c) {
        float wvv = wr[c];
        a0c[c] += a0 * wvv;
        a1c[c] += a1 * wvv;
      }
    }
    #pragma unroll
    for (int c = 0; c < 48; ++c) {
      int cg = c0 + c;
      int part = cg >> 6;     // 0=q 1=k 2=v
      int ch = cg & 63;
      float v0 = a0c[c], v1 = a1c[c];
      if (part == 0) { v0 *= 0.25f; v1 *= 0.25f; }  // q * d^-0.5
      qkvL[part][lane][ch]      = v0;
      qkvL[part][lane + 64][ch] = v1;
    }
  }
  __syncthreads();

  // ---- attention: wave = head; lane owns queries (lane, lane+64); online softmax ----
  {
    const int h   = wv;
    const int off = h * DH;
    float qA[DH], qB[DH];
    #pragma unroll
    for (int d = 0; d < DH; ++d) {
      qA[d] = qkvL[0][lane][off + d];
      qB[d] = qkvL[0][lane + 64][off + d];
    }
    float mA = -1e30f, mB = -1e30f, lA = 0.0f, lB = 0.0f;
    float oA[DH], oB[DH];
    #pragma unroll
    for (int d = 0; d < DH; ++d) { oA[d] = 0.0f; oB[d] = 0.0f; }
    const int qih = lane >> 3, qiw = lane & 7;   // query B is qih+8 -> ridx + 120
    #pragma unroll 2
    for (int j = 0; j < NT; ++j) {
      float kr[DH];
      #pragma unroll
      for (int d = 0; d < DH; ++d) kr[d] = qkvL[1][j][off + d];
      float sA = 0.0f, sB = 0.0f;
      #pragma unroll
      for (int d = 0; d < DH; ++d) { sA += qA[d] * kr[d]; sB += qB[d] * kr[d]; }
      int rA = (qih - (j >> 3) + 15) * 15 + (qiw - (j & 7) + 7);
      sA += pT[rA * 5 + h];
      sB += pT[(rA + 120) * 5 + h];
      float mA2 = fmaxf(mA, sA), mB2 = fmaxf(mB, sB);
      float cAf = __expf(mA - mA2), cBf = __expf(mB - mB2);
      float eA  = __expf(sA - mA2), eB  = __expf(sB - mB2);
      lA = lA * cAf + eA;
      lB = lB * cBf + eB;
      float vr[DH];
      #pragma unroll
      for (int d = 0; d < DH; ++d) vr[d] = qkvL[2][j][off + d];
      #pragma unroll
      for (int d = 0; d < DH; ++d) {
        oA[d] = oA[d] * cAf + eA * vr[d];
        oB[d] = oB[d] * cBf + eB * vr[d];
      }
      mA = mA2; mB = mB2;
    }
    float iA = 1.0f / lA, iB = 1.0f / lB;
    #pragma unroll
    for (int d = 0; d < DH; ++d) {
      tokL[lane][off + d]      = oA[d] * iA;   // tokL reused as attention output
      tokL[lane + 64][off + d] = oB[d] * iB;
    }
  }
  __syncthreads();

  // ---- proj (64x64) + residual scatter back to x / y ----
  {
    const int c0 = __builtin_amdgcn_readfirstlane(wv * 16);
    float p0[16], p1[16];
    #pragma unroll
    for (int c = 0; c < 16; ++c) { float bb = proj_b[c0 + c]; p0[c] = bb; p1[c] = bb; }
    const float* trA = &tokL[lane][0];
    const float* trB = &tokL[lane + 64][0];
    #pragma unroll 4
    for (int i = 0; i < CC; ++i) {
      float a0 = trA[i], a1 = trB[i];
      const float* wr = proj_w + i * CC + c0;
      #pragma unroll
      for (int c = 0; c < 16; ++c) {
        float wvv = wr[c];
        p0[c] += a0 * wvv;
        p1[c] += a1 * wvv;
      }
    }
    // token lane -> x pixel, token lane+64 -> same pixel in y
    const int g = lane;
    const long long base = ((long long)b * LL + (long long)(wh * GG + (g >> 3)) * W0c + (ww * GG + (g & 7))) * CC;
    #pragma unroll
    for (int c = 0; c < 16; ++c) out[base + c0 + c] = x[base + c0 + c] + p0[c];
    float* oy = out + MODSZ;
    #pragma unroll
    for (int c = 0; c < 16; ++c) oy[base + c0 + c] = y[base + c0 + c] + p1[c];
  }
}

// ---------------------------------------------------------------------------
// Kernel M: per-token MLP with residual.  128 tokens per block, 4 waves.
// waves {0,1} own tokens 0..63 (k-halves 0/1), waves {2,3} own tokens 64..127.
// ---------------------------------------------------------------------------
__launch_bounds__(256, 1)
__global__ void mlp_kernel(const float* __restrict__ n2g, const float* __restrict__ n2b,
                           const float* __restrict__ fx1w, const float* __restrict__ fx1b,
                           const float* __restrict__ fx2w, const float* __restrict__ fx2b,
                           const float* __restrict__ fy1w, const float* __restrict__ fy1b,
                           const float* __restrict__ fy2w, const float* __restrict__ fy2b,
                           float* __restrict__ out) {
  __shared__ float hidL[128][HIDN + 1];   // 131.6 KB

  const int tid  = threadIdx.x;
  const int lane = tid & 63;
  const int wv   = tid >> 6;

  const int blk = blockIdx.x;             // 0..2047
  const int mod = blk >> 10;              // 0=x, 1=y
  const long long tok0 = (long long)(blk & 1023) * 128;

  const float* w1 = mod ? fy1w : fx1w;
  const float* b1 = mod ? fy1b : fx1b;
  const float* w2 = mod ? fy2w : fx2w;
  const float* b2 = mod ? fy2b : fx2b;

  const int lt = ((wv >> 1) << 6) | lane;   // local token 0..127
  float* row = out + (long long)mod * MODSZ + (tok0 + lt) * CC;

  // load token row + LayerNorm(norm2), all in registers
  float v[CC];
  #pragma unroll
  for (int i = 0; i < CC / 4; ++i) {
    float4 f = ((const float4*)row)[i];
    v[4 * i + 0] = f.x; v[4 * i + 1] = f.y; v[4 * i + 2] = f.z; v[4 * i + 3] = f.w;
  }
  float s = 0.0f, s2 = 0.0f;
  #pragma unroll
  for (int i = 0; i < CC; ++i) { s += v[i]; s2 += v[i] * v[i]; }
  float mu  = s * (1.0f / 64.0f);
  float var = fmaxf(s2 * (1.0f / 64.0f) - mu * mu, 0.0f);
  float rs  = rsqrtf(var + 1e-5f);
  float nrm[CC];
  #pragma unroll
  for (int i = 0; i < CC; ++i) nrm[i] = (v[i] - mu) * rs * n2g[i] + n2b[i];

  // fc1 + exact gelu -> LDS  (this wave's k-half: 128 hidden units)
  const int k0 = __builtin_amdgcn_readfirstlane((wv & 1) * 128);
  for (int chunk = 0; chunk < 4; ++chunk) {
    const int kb = k0 + chunk * 32;
    float acc[32];
    #pragma unroll
    for (int c = 0; c < 32; ++c) acc[c] = b1[kb + c];
    #pragma unroll
    for (int i = 0; i < CC; ++i) {
      float a = nrm[i];
      const float* wr = w1 + i * HIDN + kb;
      #pragma unroll
      for (int c = 0; c < 32; ++c) acc[c] += a * wr[c];
    }
    #pragma unroll
    for (int c = 0; c < 32; ++c) {
      float u = acc[c];
      hidL[lt][kb + c] = 0.5f * u * (1.0f + erff(u * 0.70710678118654752440f));
    }
  }
  __syncthreads();

  // fc2 (this wave's c-half: 32 channels) + residual
  const int cb = __builtin_amdgcn_readfirstlane((wv & 1) * 32);
  float res[32];
  #pragma unroll
  for (int c = 0; c < 32; ++c) res[c] = b2[cb + c];
  const float* hr = &hidL[lt][0];
  #pragma unroll 4
  for (int k = 0; k < HIDN; ++k) {
    float hv = hr[k];
    const float* wr = w2 + k * CC + cb;
    #pragma unroll
    for (int c = 0; c < 32; ++c) res[c] += hv * wr[c];
  }
  if (wv & 1) {
    #pragma unroll
    for (int c = 0; c < 32; ++c) row[32 + c] = v[32 + c] + res[c];
  } else {
    #pragma unroll
    for (int c = 0; c < 32; ++c) row[c] = v[c] + res[c];
  }
}

// ---------------------------------------------------------------------------
extern "C" void kernel_launch(void* const* d_in, const int* in_sizes, int n_in,
                              void* d_out, int out_size, void* d_ws, size_t ws_size,
                              hipStream_t stream) {
  const float* x      = (const float*)d_in[0];
  const float* y      = (const float*)d_in[1];
  const float* n1g    = (const float*)d_in[2];
  const float* n1b    = (const float*)d_in[3];
  const float* qkv_w  = (const float*)d_in[4];
  const float* qkv_b  = (const float*)d_in[5];
  const float* proj_w = (const float*)d_in[6];
  const float* proj_b = (const float*)d_in[7];
  const float* pp_w   = (const float*)d_in[8];
  const float* pp_b   = (const float*)d_in[9];
  const float* ln1g   = (const float*)d_in[10];
  const float* ln1b   = (const float*)d_in[11];
  const float* l1w    = (const float*)d_in[12];
  const float* l1b    = (const float*)d_in[13];
  const float* ln2g   = (const float*)d_in[14];
  const float* ln2b   = (const float*)d_in[15];
  const float* l2w    = (const float*)d_in[16];
  const float* l2b    = (const float*)d_in[17];
  const float* ln3g   = (const float*)d_in[18];
  const float* ln3b   = (const float*)d_in[19];
  const float* l3w    = (const float*)d_in[20];
  const float* l3b    = (const float*)d_in[21];
  const float* n2g    = (const float*)d_in[22];
  const float* n2b    = (const float*)d_in[23];
  const float* fx1w   = (const float*)d_in[24];
  const float* fx1b   = (const float*)d_in[25];
  const float* fx2w   = (const float*)d_in[26];
  const float* fx2b   = (const float*)d_in[27];
  const float* fy1w   = (const float*)d_in[28];
  const float* fy1b   = (const float*)d_in[29];
  const float* fy2w   = (const float*)d_in[30];
  const float* fy2b   = (const float*)d_in[31];
  (void)in_sizes; (void)n_in; (void)out_size; (void)ws_size;

  float* out     = (float*)d_out;
  float* p_table = (float*)d_ws;   // 465*4 floats

  pbias_kernel<<<1, 512, 0, stream>>>(pp_w, pp_b, ln1g, ln1b, l1w, l1b,
                                      ln2g, ln2b, l2w, l2b, ln3g, ln3b, l3w, l3b, p_table);
  win_attn_kernel<<<NWIN, 256, 0, stream>>>(x, y, n1g, n1b, qkv_w, qkv_b,
                                            proj_w, proj_b, p_table, out);
  mlp_kernel<<<2048, 256, 0, stream>>>(n2g, n2b, fx1w, fx1b, fx2w, fx2b,
                                       fy1w, fy1b, fy2w, fy2b, out);
}

// Round 2
// 749.377 us; speedup vs baseline: 5.1072x; 5.1072x over previous
//
#include <hip/hip_runtime.h>
#include <hip/hip_bf16.h>
#include <math.h>

constexpr int CC    = 64;          // channels
constexpr int NHEAD = 4;
constexpr int DH    = 16;          // head dim
constexpr int GG    = 8;           // window size
constexpr int H0    = 256;
constexpr int W0c   = 256;
constexpr int BB    = 2;
constexpr int LL    = H0 * W0c;                     // 65536
constexpr int NWIN  = BB * (H0 / GG) * (W0c / GG);  // 2048
constexpr int NT    = 128;                          // tokens per window (2*G*G)
constexpr int HIDN  = 256;                          // MLP hidden
constexpr int NBIA  = 31 * 15;                      // 465 relative-pos entries
constexpr long long MODSZ = (long long)BB * LL * CC; // 8388608 floats per modality

using f32x4  = __attribute__((ext_vector_type(4))) float;
using bf16x8 = __attribute__((ext_vector_type(8))) short;

static __device__ __forceinline__ short to_bf16(float f) {
  unsigned u = __float_as_uint(f);
  unsigned r = (u + 0x7FFFu + ((u >> 16) & 1u)) >> 16;
  return (short)r;
}
static __device__ __forceinline__ float gelu_tanh(float u) {
  // 0.5u(1+tanh(0.79788456(u+0.044715u^3))) == u*sigmoid(1.59576912(u+0.044715u^3))
  float u2 = u * u;
  float t  = fmaf(0.044715f, u2, 1.0f);
  float z  = u * t * 1.5957691216057308f;
  float e  = __expf(-z);
  return u / (1.0f + e);
}

// ---------------------------------------------------------------------------
// Kernel P: dynamic position bias table (465 x 4) via tiny MLP
// ---------------------------------------------------------------------------
static __device__ __forceinline__ void ln4_relu(float* p, const float* g, const float* b) {
  float mu = 0.25f * (p[0] + p[1] + p[2] + p[3]);
  float d0 = p[0] - mu, d1 = p[1] - mu, d2 = p[2] - mu, d3 = p[3] - mu;
  float var = 0.25f * (d0 * d0 + d1 * d1 + d2 * d2 + d3 * d3);
  float rs = rsqrtf(var + 1e-5f);
  p[0] = fmaxf(d0 * rs * g[0] + b[0], 0.0f);
  p[1] = fmaxf(d1 * rs * g[1] + b[1], 0.0f);
  p[2] = fmaxf(d2 * rs * g[2] + b[2], 0.0f);
  p[3] = fmaxf(d3 * rs * g[3] + b[3], 0.0f);
}
static __device__ __forceinline__ void mm4(const float* a, const float* w, const float* b, float* o) {
  #pragma unroll
  for (int j = 0; j < 4; ++j) {
    float s = b[j];
    #pragma unroll
    for (int i = 0; i < 4; ++i) s += a[i] * w[i * 4 + j];
    o[j] = s;
  }
}

__global__ void pbias_kernel(const float* __restrict__ pp_w, const float* __restrict__ pp_b,
                             const float* __restrict__ ln1g, const float* __restrict__ ln1b,
                             const float* __restrict__ l1w,  const float* __restrict__ l1b,
                             const float* __restrict__ ln2g, const float* __restrict__ ln2b,
                             const float* __restrict__ l2w,  const float* __restrict__ l2b,
                             const float* __restrict__ ln3g, const float* __restrict__ ln3b,
                             const float* __restrict__ l3w,  const float* __restrict__ l3b,
                             float* __restrict__ p_table) {
  int r = blockIdx.x * blockDim.x + threadIdx.x;
  if (r >= NBIA) return;
  float bh = (float)(r / 15 - 15);   // 1-Gh .. Gh-1, Gh=16
  float bw = (float)(r % 15 - 7);    // 1-Gw .. Gw-1, Gw=8
  float a[4], t[4];
  #pragma unroll
  for (int j = 0; j < 4; ++j) a[j] = bh * pp_w[j] + bw * pp_w[4 + j] + pp_b[j];
  ln4_relu(a, ln1g, ln1b);
  mm4(a, l1w, l1b, t);
  ln4_relu(t, ln2g, ln2b);
  mm4(t, l2w, l2b, a);
  ln4_relu(a, ln3g, ln3b);
  mm4(a, l3w, l3b, t);
  #pragma unroll
  for (int j = 0; j < 4; ++j) p_table[r * 4 + j] = t[j];
}

// ---------------------------------------------------------------------------
// Kernel W: fused LN -> window gather -> QKV -> attention -> proj -> residual
// (unchanged from previous round)
// ---------------------------------------------------------------------------
__launch_bounds__(256, 1)
__global__ void win_attn_kernel(const float* __restrict__ x, const float* __restrict__ y,
                                const float* __restrict__ n1g, const float* __restrict__ n1b,
                                const float* __restrict__ qkv_w, const float* __restrict__ qkv_b,
                                const float* __restrict__ proj_w, const float* __restrict__ proj_b,
                                const float* __restrict__ p_table, float* __restrict__ out) {
  __shared__ float tokL[NT][CC + 1];       // tokens; reused as attention output
  __shared__ float qkvL[3][NT][CC + 1];    // q (pre-scaled), k, v
  __shared__ float pT[NBIA * 5];           // bias table, stride 5 to spread banks

  const int tid  = threadIdx.x;
  const int lane = tid & 63;
  const int wv   = tid >> 6;

  const int widx = blockIdx.x;
  const int b  = widx >> 10;
  const int wl = widx & 1023;
  const int wh = wl >> 5, ww = wl & 31;

  for (int t = wv; t < NT; t += 4) {
    const int g = t & 63;
    const float* src = ((t & 64) ? y : x)
        + ((long long)b * LL + (long long)(wh * GG + (g >> 3)) * W0c + (ww * GG + (g & 7))) * CC;
    float v = src[lane];
    float s = v, s2 = v * v;
    #pragma unroll
    for (int o = 32; o; o >>= 1) { s += __shfl_xor(s, o); s2 += __shfl_xor(s2, o); }
    float mu  = s * (1.0f / 64.0f);
    float var = fmaxf(s2 * (1.0f / 64.0f) - mu * mu, 0.0f);
    float rs  = rsqrtf(var + 1e-5f);
    tokL[t][lane] = (v - mu) * rs * n1g[lane] + n1b[lane];
  }
  for (int i = tid; i < NBIA * 4; i += 256) pT[(i >> 2) * 5 + (i & 3)] = p_table[i];
  __syncthreads();

  {
    const int c0 = __builtin_amdgcn_readfirstlane(wv * 48);
    float a0c[48], a1c[48];
    #pragma unroll
    for (int c = 0; c < 48; ++c) { float bb = qkv_b[c0 + c]; a0c[c] = bb; a1c[c] = bb; }
    const float* trA = &tokL[lane][0];
    const float* trB = &tokL[lane + 64][0];
    #pragma unroll 4
    for (int i = 0; i < CC; ++i) {
      float a0 = trA[i], a1 = trB[i];
      const float* wr = qkv_w + i * (3 * CC) + c0;
      #pragma unroll
      for (int c = 0; c < 48; ++c) {
        float wvv = wr[c];
        a0c[c] += a0 * wvv;
        a1c[c] += a1 * wvv;
      }
    }
    #pragma unroll
    for (int c = 0; c < 48; ++c) {
      int cg = c0 + c;
      int part = cg >> 6;     // 0=q 1=k 2=v
      int ch = cg & 63;
      float v0 = a0c[c], v1 = a1c[c];
      if (part == 0) { v0 *= 0.25f; v1 *= 0.25f; }  // q * d^-0.5
      qkvL[part][lane][ch]      = v0;
      qkvL[part][lane + 64][ch] = v1;
    }
  }
  __syncthreads();

  {
    const int h   = wv;
    const int off = h * DH;
    float qA[DH], qB[DH];
    #pragma unroll
    for (int d = 0; d < DH; ++d) {
      qA[d] = qkvL[0][lane][off + d];
      qB[d] = qkvL[0][lane + 64][off + d];
    }
    float mA = -1e30f, mB = -1e30f, lA = 0.0f, lB = 0.0f;
    float oA[DH], oB[DH];
    #pragma unroll
    for (int d = 0; d < DH; ++d) { oA[d] = 0.0f; oB[d] = 0.0f; }
    const int qih = lane >> 3, qiw = lane & 7;
    #pragma unroll 2
    for (int j = 0; j < NT; ++j) {
      float kr[DH];
      #pragma unroll
      for (int d = 0; d < DH; ++d) kr[d] = qkvL[1][j][off + d];
      float sA = 0.0f, sB = 0.0f;
      #pragma unroll
      for (int d = 0; d < DH; ++d) { sA += qA[d] * kr[d]; sB += qB[d] * kr[d]; }
      int rA = (qih - (j >> 3) + 15) * 15 + (qiw - (j & 7) + 7);
      sA += pT[rA * 5 + h];
      sB += pT[(rA + 120) * 5 + h];
      float mA2 = fmaxf(mA, sA), mB2 = fmaxf(mB, sB);
      float cAf = __expf(mA - mA2), cBf = __expf(mB - mB2);
      float eA  = __expf(sA - mA2), eB  = __expf(sB - mB2);
      lA = lA * cAf + eA;
      lB = lB * cBf + eB;
      float vr[DH];
      #pragma unroll
      for (int d = 0; d < DH; ++d) vr[d] = qkvL[2][j][off + d];
      #pragma unroll
      for (int d = 0; d < DH; ++d) {
        oA[d] = oA[d] * cAf + eA * vr[d];
        oB[d] = oB[d] * cBf + eB * vr[d];
      }
      mA = mA2; mB = mB2;
    }
    float iA = 1.0f / lA, iB = 1.0f / lB;
    #pragma unroll
    for (int d = 0; d < DH; ++d) {
      tokL[lane][off + d]      = oA[d] * iA;
      tokL[lane + 64][off + d] = oB[d] * iB;
    }
  }
  __syncthreads();

  {
    const int c0 = __builtin_amdgcn_readfirstlane(wv * 16);
    float p0[16], p1[16];
    #pragma unroll
    for (int c = 0; c < 16; ++c) { float bb = proj_b[c0 + c]; p0[c] = bb; p1[c] = bb; }
    const float* trA = &tokL[lane][0];
    const float* trB = &tokL[lane + 64][0];
    #pragma unroll 4
    for (int i = 0; i < CC; ++i) {
      float a0 = trA[i], a1 = trB[i];
      const float* wr = proj_w + i * CC + c0;
      #pragma unroll
      for (int c = 0; c < 16; ++c) {
        float wvv = wr[c];
        p0[c] += a0 * wvv;
        p1[c] += a1 * wvv;
      }
    }
    const int g = lane;
    const long long base = ((long long)b * LL + (long long)(wh * GG + (g >> 3)) * W0c + (ww * GG + (g & 7))) * CC;
    #pragma unroll
    for (int c = 0; c < 16; ++c) out[base + c0 + c] = x[base + c0 + c] + p0[c];
    float* oy = out + MODSZ;
    #pragma unroll
    for (int c = 0; c < 16; ++c) oy[base + c0 + c] = y[base + c0 + c] + p1[c];
  }
}

// ---------------------------------------------------------------------------
// Kernel M (rewritten): MFMA bf16 MLP.
// 1024 blocks x 256 thr (4 waves). Wave owns 64 tokens. Block covers 256
// tokens of one modality. Weights staged once per block in MFMA-frag order.
// mfma_f32_16x16x32_bf16: A row=lane&15, k=(lane>>4)*8+j; B col=lane&15,
// same k; D col=lane&15, row=(lane>>4)*4+reg  [m89/m97-verified layouts].
// ---------------------------------------------------------------------------
__launch_bounds__(256, 1)
__global__ void mlp_mfma_kernel(const float* __restrict__ n2g, const float* __restrict__ n2b,
                                const float* __restrict__ fx1w, const float* __restrict__ fx1b,
                                const float* __restrict__ fx2w, const float* __restrict__ fx2b,
                                const float* __restrict__ fy1w, const float* __restrict__ fy1b,
                                const float* __restrict__ fy2w, const float* __restrict__ fy2b,
                                float* __restrict__ out) {
  __shared__ short W1F[16384];                       // 32 KB: 32 slots x 512 shorts
  __shared__ short W2F[16384];                       // 32 KB
  __shared__ __align__(16) char ARENA[4][16384];     // 16 KB per wave

  const int tid = threadIdx.x;
  const int l   = tid & 63;
  const int wv  = tid >> 6;
  const int bid = blockIdx.x;
  const int mod = bid >> 9;                          // 0=x, 1=y
  const long long tok0 = (long long)(bid & 511) * 256;

  const float* w1 = mod ? fy1w : fx1w;
  const float* b1 = mod ? fy1b : fx1b;
  const float* w2 = mod ? fy2w : fx2w;
  const float* b2 = mod ? fy2b : fx2b;
  float* const outm = out + (long long)mod * MODSZ;

  // ---- stage both weight matrices into frag-ordered bf16 LDS ----
  #pragma unroll 4
  for (int it = 0; it < 64; ++it) {
    int idx = it * 256 + tid;
    {
      int k = idx >> 8, col = idx & 255;             // w1[k][col], (64 x 256)
      short h = to_bf16(w1[idx]);
      int lanep = (((k >> 3) & 3) << 4) | (col & 15);
      int slot  = ((col >> 4) << 1) | (k >> 5);      // tile*2 + kstep
      W1F[(slot << 9) + (lanep << 3) + (k & 7)] = h;
    }
    {
      int k = idx >> 6, col = idx & 63;              // w2[k][col], (256 x 64)
      short h = to_bf16(w2[idx]);
      int lanep = (((k >> 3) & 3) << 4) | (col & 15);
      int slot  = ((col >> 4) << 3) | (k >> 5);      // tile*8 + kstep(0..7)
      W2F[(slot << 9) + (lanep << 3) + (k & 7)] = h;
    }
  }

  // ---- LN of this wave's 64 token rows (lane = token), bf16 A-tile in LDS ----
  char* const AR = ARENA[wv];
  {
    const float* rowp = outm + (tok0 + (long long)(wv * 64 + l)) * CC;
    float v[CC];
    #pragma unroll
    for (int i = 0; i < 16; ++i) {
      float4 f = ((const float4*)rowp)[i];
      v[4 * i] = f.x; v[4 * i + 1] = f.y; v[4 * i + 2] = f.z; v[4 * i + 3] = f.w;
    }
    float s = 0.0f, s2 = 0.0f;
    #pragma unroll
    for (int i = 0; i < CC; ++i) { s += v[i]; s2 += v[i] * v[i]; }
    float mu  = s * (1.0f / 64.0f);
    float var = fmaxf(s2 * (1.0f / 64.0f) - mu * mu, 0.0f);
    float rs  = rsqrtf(var + 1e-5f);
    #pragma unroll
    for (int c = 0; c < 8; ++c) {
      bf16x8 w;
      #pragma unroll
      for (int j = 0; j < 8; ++j) {
        int ch = c * 8 + j;
        w[j] = to_bf16((v[ch] - mu) * rs * n2g[ch] + n2b[ch]);
      }
      *(bf16x8*)(AR + l * 128 + ((c * 16) ^ ((l & 7) << 4))) = w;   // T2 swizzle
    }
  }
  __syncthreads();

  // ---- fc1 A-frags (token tile), persistent ----
  bf16x8 afa[4][2];
  #pragma unroll
  for (int m = 0; m < 4; ++m) {
    int row = 16 * m + (l & 15);
    #pragma unroll
    for (int s = 0; s < 2; ++s)
      afa[m][s] = *(const bf16x8*)(AR + row * 128 + ((64 * s + ((l >> 4) << 4)) ^ ((row & 7) << 4)));
  }

  // ---- fc2 accumulators, init with bias ----
  f32x4 acc2[4][4];
  #pragma unroll
  for (int n = 0; n < 4; ++n) {
    float bb = b2[16 * n + (l & 15)];
    #pragma unroll
    for (int m = 0; m < 4; ++m) { acc2[m][n][0] = bb; acc2[m][n][1] = bb; acc2[m][n][2] = bb; acc2[m][n][3] = bb; }
  }

  char* const HB = AR + 8192;   // per-wave hid chunk [64 tok][64 k] bf16, swizzled

  #pragma unroll 1
  for (int g = 0; g < 4; ++g) {
    // fc1: hid[:, 64g .. 64g+63]
    bf16x8 bf[4][2];
    #pragma unroll
    for (int n = 0; n < 4; ++n)
      #pragma unroll
      for (int s = 0; s < 2; ++s)
        bf[n][s] = *(const bf16x8*)(W1F + ((((g * 4 + n) * 2 + s) << 9) + (l << 3)));
    f32x4 a1[4][4];
    #pragma unroll
    for (int m = 0; m < 4; ++m)
      #pragma unroll
      for (int n = 0; n < 4; ++n) {
        f32x4 z = {0.0f, 0.0f, 0.0f, 0.0f};
        z = __builtin_amdgcn_mfma_f32_16x16x32_bf16(afa[m][0], bf[n][0], z, 0, 0, 0);
        a1[m][n] = __builtin_amdgcn_mfma_f32_16x16x32_bf16(afa[m][1], bf[n][1], z, 0, 0, 0);
      }
    // bias + gelu -> bf16 hid LDS
    float b1v[4];
    #pragma unroll
    for (int n = 0; n < 4; ++n) b1v[n] = b1[g * 64 + 16 * n + (l & 15)];
    #pragma unroll
    for (int m = 0; m < 4; ++m)
      #pragma unroll
      for (int n = 0; n < 4; ++n)
        #pragma unroll
        for (int r = 0; r < 4; ++r) {
          float u = a1[m][n][r] + b1v[n];
          int row = 16 * m + ((l >> 4) << 2) + r;
          *(short*)(HB + row * 128 + (((16 * n + (l & 15)) << 1) ^ ((row & 7) << 4))) = to_bf16(gelu_tanh(u));
        }
    // fc2 partial: out += hid_chunk @ w2[64g:64g+64, :]
    bf16x8 a2[4][2], b2f[4][2];
    #pragma unroll
    for (int m = 0; m < 4; ++m) {
      int row = 16 * m + (l & 15);
      #pragma unroll
      for (int s = 0; s < 2; ++s)
        a2[m][s] = *(const bf16x8*)(HB + row * 128 + ((64 * s + ((l >> 4) << 4)) ^ ((row & 7) << 4)));
    }
    #pragma unroll
    for (int n = 0; n < 4; ++n)
      #pragma unroll
      for (int s = 0; s < 2; ++s)
        b2f[n][s] = *(const bf16x8*)(W2F + (((n * 8 + g * 2 + s) << 9) + (l << 3)));
    #pragma unroll
    for (int m = 0; m < 4; ++m)
      #pragma unroll
      for (int n = 0; n < 4; ++n) {
        acc2[m][n] = __builtin_amdgcn_mfma_f32_16x16x32_bf16(a2[m][0], b2f[n][0], acc2[m][n], 0, 0, 0);
        acc2[m][n] = __builtin_amdgcn_mfma_f32_16x16x32_bf16(a2[m][1], b2f[n][1], acc2[m][n], 0, 0, 0);
      }
  }

  // ---- epilogue: f32 bounce through per-wave arena for coalesced residual ----
  float* const OF = (float*)AR;   // [64 tok][64 ch] f32 (A-tile/hid are dead)
  #pragma unroll
  for (int m = 0; m < 4; ++m)
    #pragma unroll
    for (int n = 0; n < 4; ++n)
      #pragma unroll
      for (int r = 0; r < 4; ++r) {
        int row = 16 * m + ((l >> 4) << 2) + r;
        OF[row * 64 + 16 * n + (l & 15)] = acc2[m][n][r];
      }
  #pragma unroll
  for (int i = 0; i < 16; ++i) {
    int row = i * 4 + (l >> 4);
    f32x4 v4 = *(const f32x4*)(OF + row * 64 + ((l & 15) << 2));
    float* rp = outm + (tok0 + (long long)(wv * 64 + row)) * CC + ((l & 15) << 2);
    float4 g4 = *(const float4*)rp;
    float4 o;
    o.x = g4.x + v4[0]; o.y = g4.y + v4[1]; o.z = g4.z + v4[2]; o.w = g4.w + v4[3];
    *(float4*)rp = o;
  }
}

// ---------------------------------------------------------------------------
extern "C" void kernel_launch(void* const* d_in, const int* in_sizes, int n_in,
                              void* d_out, int out_size, void* d_ws, size_t ws_size,
                              hipStream_t stream) {
  const float* x      = (const float*)d_in[0];
  const float* y      = (const float*)d_in[1];
  const float* n1g    = (const float*)d_in[2];
  const float* n1b    = (const float*)d_in[3];
  const float* qkv_w  = (const float*)d_in[4];
  const float* qkv_b  = (const float*)d_in[5];
  const float* proj_w = (const float*)d_in[6];
  const float* proj_b = (const float*)d_in[7];
  const float* pp_w   = (const float*)d_in[8];
  const float* pp_b   = (const float*)d_in[9];
  const float* ln1g   = (const float*)d_in[10];
  const float* ln1b   = (const float*)d_in[11];
  const float* l1w    = (const float*)d_in[12];
  const float* l1b    = (const float*)d_in[13];
  const float* ln2g   = (const float*)d_in[14];
  const float* ln2b   = (const float*)d_in[15];
  const float* l2w    = (const float*)d_in[16];
  const float* l2b    = (const float*)d_in[17];
  const float* ln3g   = (const float*)d_in[18];
  const float* ln3b   = (const float*)d_in[19];
  const float* l3w    = (const float*)d_in[20];
  const float* l3b    = (const float*)d_in[21];
  const float* n2g    = (const float*)d_in[22];
  const float* n2b    = (const float*)d_in[23];
  const float* fx1w   = (const float*)d_in[24];
  const float* fx1b   = (const float*)d_in[25];
  const float* fx2w   = (const float*)d_in[26];
  const float* fx2b   = (const float*)d_in[27];
  const float* fy1w   = (const float*)d_in[28];
  const float* fy1b   = (const float*)d_in[29];
  const float* fy2w   = (const float*)d_in[30];
  const float* fy2b   = (const float*)d_in[31];
  (void)in_sizes; (void)n_in; (void)out_size; (void)ws_size;

  float* out     = (float*)d_out;
  float* p_table = (float*)d_ws;   // 465*4 floats

  pbias_kernel<<<1, 512, 0, stream>>>(pp_w, pp_b, ln1g, ln1b, l1w, l1b,
                                      ln2g, ln2b, l2w, l2b, ln3g, ln3b, l3w, l3b, p_table);
  win_attn_kernel<<<NWIN, 256, 0, stream>>>(x, y, n1g, n1b, qkv_w, qkv_b,
                                            proj_w, proj_b, p_table, out);
  mlp_mfma_kernel<<<1024, 256, 0, stream>>>(n2g, n2b, fx1w, fx1b, fx2w, fx2b,
                                            fy1w, fy1b, fy2w, fy2b, out);
}

// Round 3
// 227.097 us; speedup vs baseline: 16.8529x; 3.2998x over previous
//
#include <hip/hip_runtime.h>
#include <math.h>

constexpr int CC    = 64;          // channels
constexpr int GG    = 8;           // window size
constexpr int H0    = 256;
constexpr int W0c   = 256;
constexpr int BB    = 2;
constexpr int LL    = H0 * W0c;                     // 65536
constexpr int NWIN  = BB * (H0 / GG) * (W0c / GG);  // 2048
constexpr int HIDN  = 256;                          // MLP hidden
constexpr int NBIA  = 31 * 15;                      // 465 relative-pos entries
constexpr long long MODSZ = (long long)BB * LL * CC; // 8388608 floats per modality

// ws byte offsets
constexpr int WS_PTAB  = 0;        // 465*4 f32
constexpr int WS_BIAS  = 8192;     // [4][128][128] f32 = 256 KB
constexpr int WS_WQKV  = 270336;   // 24 slots * 512 bf16 = 24 KB (B-frag image)
constexpr int WS_WPROJ = 294912;   // 8 slots * 512 bf16 = 8 KB

using f32x4  = __attribute__((ext_vector_type(4))) float;
using bf16x8 = __attribute__((ext_vector_type(8))) short;
using bf16x4 = __attribute__((ext_vector_type(4))) short;

static __device__ __forceinline__ short to_bf16(float f) {
  unsigned u = __float_as_uint(f);
  unsigned r = (u + 0x7FFFu + ((u >> 16) & 1u)) >> 16;
  return (short)r;
}
static __device__ __forceinline__ float gelu_tanh(float u) {
  float u2 = u * u;
  float t  = fmaf(0.044715f, u2, 1.0f);
  float z  = u * t * 1.5957691216057308f;
  float e  = __expf(-z);
  return u / (1.0f + e);
}

// ---------------------------------------------------------------------------
// Kernel P: dynamic position bias table (465 x 4) via tiny MLP
// ---------------------------------------------------------------------------
static __device__ __forceinline__ void ln4_relu(float* p, const float* g, const float* b) {
  float mu = 0.25f * (p[0] + p[1] + p[2] + p[3]);
  float d0 = p[0] - mu, d1 = p[1] - mu, d2 = p[2] - mu, d3 = p[3] - mu;
  float var = 0.25f * (d0 * d0 + d1 * d1 + d2 * d2 + d3 * d3);
  float rs = rsqrtf(var + 1e-5f);
  p[0] = fmaxf(d0 * rs * g[0] + b[0], 0.0f);
  p[1] = fmaxf(d1 * rs * g[1] + b[1], 0.0f);
  p[2] = fmaxf(d2 * rs * g[2] + b[2], 0.0f);
  p[3] = fmaxf(d3 * rs * g[3] + b[3], 0.0f);
}
static __device__ __forceinline__ void mm4(const float* a, const float* w, const float* b, float* o) {
  #pragma unroll
  for (int j = 0; j < 4; ++j) {
    float s = b[j];
    #pragma unroll
    for (int i = 0; i < 4; ++i) s += a[i] * w[i * 4 + j];
    o[j] = s;
  }
}

__global__ void pbias_kernel(const float* __restrict__ pp_w, const float* __restrict__ pp_b,
                             const float* __restrict__ ln1g, const float* __restrict__ ln1b,
                             const float* __restrict__ l1w,  const float* __restrict__ l1b,
                             const float* __restrict__ ln2g, const float* __restrict__ ln2b,
                             const float* __restrict__ l2w,  const float* __restrict__ l2b,
                             const float* __restrict__ ln3g, const float* __restrict__ ln3b,
                             const float* __restrict__ l3w,  const float* __restrict__ l3b,
                             float* __restrict__ p_table) {
  int r = blockIdx.x * blockDim.x + threadIdx.x;
  if (r >= NBIA) return;
  float bh = (float)(r / 15 - 15);
  float bw = (float)(r % 15 - 7);
  float a[4], t[4];
  #pragma unroll
  for (int j = 0; j < 4; ++j) a[j] = bh * pp_w[j] + bw * pp_w[4 + j] + pp_b[j];
  ln4_relu(a, ln1g, ln1b);
  mm4(a, l1w, l1b, t);
  ln4_relu(t, ln2g, ln2b);
  mm4(t, l2w, l2b, a);
  ln4_relu(a, ln3g, ln3b);
  mm4(a, l3w, l3b, t);
  #pragma unroll
  for (int j = 0; j < 4; ++j) p_table[r * 4 + j] = t[j];
}

// ---------------------------------------------------------------------------
// bias_expand: p_table (465x4) -> dense bias_exp[h][q][k] f32 (4x128x128)
// ---------------------------------------------------------------------------
__global__ void bias_expand_kernel(const float* __restrict__ p_table, float* __restrict__ bias_exp) {
  int gid = blockIdx.x * 256 + threadIdx.x;   // 16384 float4's
  int h   = gid >> 12;
  int rem = gid & 4095;
  int q   = rem >> 5;
  int k0  = (rem & 31) * 4;
  int qih = q >> 3, qiw = q & 7;
  float o[4];
  #pragma unroll
  for (int kk = 0; kk < 4; ++kk) {
    int k = k0 + kk;
    int ridx = (qih - (k >> 3) + 15) * 15 + (qiw - (k & 7) + 7);
    o[kk] = p_table[ridx * 4 + h];
  }
  f32x4 v = {o[0], o[1], o[2], o[3]};
  *(f32x4*)(bias_exp + gid * 4) = v;
}

// ---------------------------------------------------------------------------
// prep_w: qkv_w/proj_w f32 -> bf16 B-fragment images (16x16x32 layout:
// B[k][col]: col=lane&15, k=(lane>>4)*8+j; slot = ntile*2 + kstep).
// q-scale (d^-0.5 = 0.25) folded into q columns.
// ---------------------------------------------------------------------------
__global__ void prep_w_kernel(const float* __restrict__ qkv_w, const float* __restrict__ proj_w,
                              short* __restrict__ wqkvF, short* __restrict__ projF) {
  int t = blockIdx.x * 256 + threadIdx.x;    // 16384
  if (t < 12288) {
    int slot = t >> 9, e = t & 511;
    int lp = e >> 3, j = e & 7;
    int ng = slot >> 1, s = slot & 1;
    int k   = 32 * s + 8 * (lp >> 4) + j;
    int col = 16 * ng + (lp & 15);
    float v = qkv_w[k * 192 + col];
    if (col < 64) v *= 0.25f;
    wqkvF[t] = to_bf16(v);
  } else {
    int t2 = t - 12288;
    int slot = t2 >> 9, e = t2 & 511;
    int lp = e >> 3, j = e & 7;
    int ng = slot >> 1, s = slot & 1;
    int k   = 32 * s + 8 * (lp >> 4) + j;
    int col = 16 * ng + (lp & 15);
    projF[t2] = to_bf16(proj_w[k * 64 + col]);
  }
}

// ---------------------------------------------------------------------------
// Kernel W v2: all-MFMA fused window attention.
// Block = window (2048), 256 thr = 4 waves. LDS 80 KB -> 2 blocks/CU.
// LDS: TOK [128][64]bf16 (A-tile, reused as attn-out) | QB | KB [128][64]bf16
//      | VT [64][128]bf16 | PB 4x[16][128]bf16. All XOR-swizzled ^((row&7)<<4).
// ---------------------------------------------------------------------------
__launch_bounds__(256, 2)
__global__ void win_attn_kernel(const float* __restrict__ x, const float* __restrict__ y,
                                const float* __restrict__ n1g, const float* __restrict__ n1b,
                                const float* __restrict__ qkv_b, const float* __restrict__ proj_b,
                                const float* __restrict__ bias_exp,
                                const short* __restrict__ wqkvF, const short* __restrict__ projF,
                                float* __restrict__ out) {
  __shared__ __align__(16) char smem[81920];
  char* const TOK_ = smem;            // 16 KB
  char* const QB_  = smem + 16384;    // 16 KB
  char* const KB_  = smem + 32768;    // 16 KB
  char* const VT_  = smem + 49152;    // 16 KB
  char* const PB_  = smem + 65536;    // 16 KB (4 KB per wave)

  const int tid = threadIdx.x;
  const int l   = tid & 63;
  const int l15 = l & 15;
  const int lg  = l >> 4;
  const int wv  = __builtin_amdgcn_readfirstlane(tid >> 6);

  const int widx = blockIdx.x;
  const int b  = widx >> 10;
  const int wl = widx & 1023;
  const int wh = wl >> 5, ww = wl & 31;

  // ---- phase 1: gather + LN -> bf16 A-tile (swizzled) ----
  {
    const int lane16 = tid & 15;
    const float4 g4 = *(const float4*)(n1g + lane16 * 4);
    const float4 b4 = *(const float4*)(n1b + lane16 * 4);
    #pragma unroll
    for (int ps = 0; ps < 8; ++ps) {
      int t  = ps * 16 + (tid >> 4);
      int g  = t & 63;
      const float* src = ((t & 64) ? y : x)
          + ((long long)b * LL + (long long)(wh * GG + (g >> 3)) * W0c + (ww * GG + (g & 7))) * CC
          + lane16 * 4;
      float4 v = *(const float4*)src;
      float s  = v.x + v.y + v.z + v.w;
      float s2 = v.x * v.x + v.y * v.y + v.z * v.z + v.w * v.w;
      #pragma unroll
      for (int m = 1; m < 16; m <<= 1) { s += __shfl_xor(s, m); s2 += __shfl_xor(s2, m); }
      float mu  = s * (1.0f / 64.0f);
      float var = fmaxf(s2 * (1.0f / 64.0f) - mu * mu, 0.0f);
      float rs  = rsqrtf(var + 1e-5f);
      bf16x4 w4 = { to_bf16((v.x - mu) * rs * g4.x + b4.x),
                    to_bf16((v.y - mu) * rs * g4.y + b4.y),
                    to_bf16((v.z - mu) * rs * g4.z + b4.z),
                    to_bf16((v.w - mu) * rs * g4.w + b4.w) };
      *(bf16x4*)(TOK_ + ((t * 128 + lane16 * 8) ^ ((t & 7) << 4))) = w4;
    }
  }
  __syncthreads();

  // ---- phase 2: QKV GEMM (wave owns 48 out channels = 3 N-tiles) ----
  {
    bf16x8 wb[3][2];
    #pragma unroll
    for (int nt = 0; nt < 3; ++nt)
      #pragma unroll
      for (int s = 0; s < 2; ++s)
        wb[nt][s] = *(const bf16x8*)((const char*)wqkvF + (((3 * wv + nt) * 2 + s) << 10) + l * 16);

    f32x4 acc[8][3];
    #pragma unroll
    for (int nt = 0; nt < 3; ++nt) {
      int col = 48 * wv + 16 * nt + l15;
      float bb = qkv_b[col];
      if (col < 64) bb *= 0.25f;
      #pragma unroll
      for (int mt = 0; mt < 8; ++mt) { acc[mt][nt][0] = bb; acc[mt][nt][1] = bb; acc[mt][nt][2] = bb; acc[mt][nt][3] = bb; }
    }
    #pragma unroll
    for (int mt = 0; mt < 8; ++mt) {
      int row = 16 * mt + l15;
      bf16x8 a0 = *(const bf16x8*)(TOK_ + ((row * 128 +      lg * 16) ^ ((row & 7) << 4)));
      bf16x8 a1 = *(const bf16x8*)(TOK_ + ((row * 128 + 64 + lg * 16) ^ ((row & 7) << 4)));
      #pragma unroll
      for (int nt = 0; nt < 3; ++nt) {
        acc[mt][nt] = __builtin_amdgcn_mfma_f32_16x16x32_bf16(a0, wb[nt][0], acc[mt][nt], 0, 0, 0);
        acc[mt][nt] = __builtin_amdgcn_mfma_f32_16x16x32_bf16(a1, wb[nt][1], acc[mt][nt], 0, 0, 0);
      }
    }
    // epilogue: scatter into Q/K [tok][64] or V^T [64][tok] bf16
    #pragma unroll
    for (int nt = 0; nt < 3; ++nt) {
      int cb = 48 * wv + 16 * nt;          // wave-uniform
      int part = cb >> 6;
      int chl = (cb & 63) + l15;
      if (part < 2) {
        char* buf = part ? KB_ : QB_;
        #pragma unroll
        for (int mt = 0; mt < 8; ++mt)
          #pragma unroll
          for (int r = 0; r < 4; ++r) {
            int tok = 16 * mt + lg * 4 + r;
            *(short*)(buf + ((tok * 128 + chl * 2) ^ ((tok & 7) << 4))) = to_bf16(acc[mt][nt][r]);
          }
      } else {
        #pragma unroll
        for (int mt = 0; mt < 8; ++mt) {
          bf16x4 w4 = { to_bf16(acc[mt][nt][0]), to_bf16(acc[mt][nt][1]),
                        to_bf16(acc[mt][nt][2]), to_bf16(acc[mt][nt][3]) };
          int tok0 = 16 * mt + lg * 4;
          *(bf16x4*)(VT_ + ((chl * 256 + tok0 * 2) ^ ((chl & 7) << 4))) = w4;
        }
      }
    }
  }
  __syncthreads();

  // ---- phase 3: attention, wave = head. Swapped QK^T (S^T = K x Q). ----
  {
    const int h = wv;
    const float* biasH = bias_exp + h * 16384;
    // K A-frags: row = k-token, kslot = d (0..15 real, 16..31 zero)
    bf16x8 kf[8];
    #pragma unroll
    for (int kt = 0; kt < 8; ++kt) {
      bf16x8 f = {0, 0, 0, 0, 0, 0, 0, 0};
      if (l < 32) {
        int row = 16 * kt + l15;
        f = *(const bf16x8*)(KB_ + ((row * 128 + h * 32 + lg * 16) ^ ((row & 7) << 4)));
      }
      kf[kt] = f;
    }
    // V B-frags: col = d, kslot = token
    bf16x8 vf[4];
    #pragma unroll
    for (int ks = 0; ks < 4; ++ks) {
      int row = h * 16 + l15;
      vf[ks] = *(const bf16x8*)(VT_ + ((row * 256 + ks * 64 + lg * 16) ^ ((row & 7) << 4)));
    }
    char* const PBw = PB_ + wv * 4096;

    for (int qt = 0; qt < 8; ++qt) {
      // bias prefetch: q = 16qt + l15 per lane; 4 consecutive k per reg group
      f32x4 bias[8];
      #pragma unroll
      for (int kt = 0; kt < 8; ++kt)
        bias[kt] = *(const f32x4*)(biasH + (16 * qt + l15) * 128 + 16 * kt + 4 * lg);
      bf16x8 qf = {0, 0, 0, 0, 0, 0, 0, 0};
      if (l < 32) {
        int row = 16 * qt + l15;
        qf = *(const bf16x8*)(QB_ + ((row * 128 + h * 32 + lg * 16) ^ ((row & 7) << 4)));
      }
      f32x4 s[8];
      #pragma unroll
      for (int kt = 0; kt < 8; ++kt) {
        f32x4 z = {0.0f, 0.0f, 0.0f, 0.0f};
        s[kt] = __builtin_amdgcn_mfma_f32_16x16x32_bf16(kf[kt], qf, z, 0, 0, 0);
      }
      // bias add + row max (q = lane&15; in-lane 32 vals + xor16 + xor32)
      float m = -1e30f;
      #pragma unroll
      for (int kt = 0; kt < 8; ++kt) {
        s[kt][0] += bias[kt][0]; s[kt][1] += bias[kt][1];
        s[kt][2] += bias[kt][2]; s[kt][3] += bias[kt][3];
        m = fmaxf(m, fmaxf(fmaxf(s[kt][0], s[kt][1]), fmaxf(s[kt][2], s[kt][3])));
      }
      m = fmaxf(m, __shfl_xor(m, 16));
      m = fmaxf(m, __shfl_xor(m, 32));
      float sum = 0.0f;
      #pragma unroll
      for (int kt = 0; kt < 8; ++kt) {
        s[kt][0] = __expf(s[kt][0] - m); s[kt][1] = __expf(s[kt][1] - m);
        s[kt][2] = __expf(s[kt][2] - m); s[kt][3] = __expf(s[kt][3] - m);
        sum += (s[kt][0] + s[kt][1]) + (s[kt][2] + s[kt][3]);
      }
      sum += __shfl_xor(sum, 16);
      sum += __shfl_xor(sum, 32);
      float inv = 1.0f / sum;
      // write normalized P^T chunk -> PBw [16 q][128 k]
      #pragma unroll
      for (int kt = 0; kt < 8; ++kt) {
        bf16x4 pw = { to_bf16(s[kt][0] * inv), to_bf16(s[kt][1] * inv),
                      to_bf16(s[kt][2] * inv), to_bf16(s[kt][3] * inv) };
        int k0 = 16 * kt + 4 * lg;
        *(bf16x4*)(PBw + ((l15 * 256 + k0 * 2) ^ ((l15 & 7) << 4))) = pw;
      }
      // PV: A = P[q][k], B = V[k][d]
      f32x4 pacc = {0.0f, 0.0f, 0.0f, 0.0f};
      #pragma unroll
      for (int ks = 0; ks < 4; ++ks) {
        bf16x8 pa = *(const bf16x8*)(PBw + ((l15 * 256 + ks * 64 + lg * 16) ^ ((l15 & 7) << 4)));
        pacc = __builtin_amdgcn_mfma_f32_16x16x32_bf16(pa, vf[ks], pacc, 0, 0, 0);
      }
      // attn-out -> TOK (col = h*16 + l15, row = tok)
      #pragma unroll
      for (int r = 0; r < 4; ++r) {
        int tok = 16 * qt + lg * 4 + r;
        *(short*)(TOK_ + ((tok * 128 + (h * 16 + l15) * 2) ^ ((tok & 7) << 4))) = to_bf16(pacc[r]);
      }
    }
  }
  __syncthreads();

  // ---- phase 4: proj (wave owns 16 out channels) + residual ----
  {
    bf16x8 pb[2];
    #pragma unroll
    for (int s = 0; s < 2; ++s)
      pb[s] = *(const bf16x8*)((const char*)projF + (((wv << 1) + s) << 10) + l * 16);
    const int ch = 16 * wv + l15;
    const float bb = proj_b[ch];
    #pragma unroll
    for (int mt = 0; mt < 8; ++mt) {
      int row = 16 * mt + l15;
      bf16x8 a0 = *(const bf16x8*)(TOK_ + ((row * 128 +      lg * 16) ^ ((row & 7) << 4)));
      bf16x8 a1 = *(const bf16x8*)(TOK_ + ((row * 128 + 64 + lg * 16) ^ ((row & 7) << 4)));
      f32x4 acc = {bb, bb, bb, bb};
      acc = __builtin_amdgcn_mfma_f32_16x16x32_bf16(a0, pb[0], acc, 0, 0, 0);
      acc = __builtin_amdgcn_mfma_f32_16x16x32_bf16(a1, pb[1], acc, 0, 0, 0);
      #pragma unroll
      for (int r = 0; r < 4; ++r) {
        int tok = 16 * mt + lg * 4 + r;
        int g   = tok & 63;
        long long base = ((long long)b * LL + (long long)(wh * GG + (g >> 3)) * W0c + (ww * GG + (g & 7))) * CC + ch;
        const float* src = ((tok & 64) ? y : x) + base;
        float* dst = out + ((tok & 64) ? MODSZ : 0) + base;
        *dst = *src + acc[r];
      }
    }
  }
}

// ---------------------------------------------------------------------------
// Kernel M: MFMA bf16 MLP (unchanged from previous round)
// ---------------------------------------------------------------------------
__launch_bounds__(256, 1)
__global__ void mlp_mfma_kernel(const float* __restrict__ n2g, const float* __restrict__ n2b,
                                const float* __restrict__ fx1w, const float* __restrict__ fx1b,
                                const float* __restrict__ fx2w, const float* __restrict__ fx2b,
                                const float* __restrict__ fy1w, const float* __restrict__ fy1b,
                                const float* __restrict__ fy2w, const float* __restrict__ fy2b,
                                float* __restrict__ out) {
  __shared__ short W1F[16384];
  __shared__ short W2F[16384];
  __shared__ __align__(16) char ARENA[4][16384];

  const int tid = threadIdx.x;
  const int l   = tid & 63;
  const int wv  = tid >> 6;
  const int bid = blockIdx.x;
  const int mod = bid >> 9;
  const long long tok0 = (long long)(bid & 511) * 256;

  const float* w1 = mod ? fy1w : fx1w;
  const float* b1 = mod ? fy1b : fx1b;
  const float* w2 = mod ? fy2w : fx2w;
  const float* b2 = mod ? fy2b : fx2b;
  float* const outm = out + (long long)mod * MODSZ;

  #pragma unroll 4
  for (int it = 0; it < 64; ++it) {
    int idx = it * 256 + tid;
    {
      int k = idx >> 8, col = idx & 255;
      short h = to_bf16(w1[idx]);
      int lanep = (((k >> 3) & 3) << 4) | (col & 15);
      int slot  = ((col >> 4) << 1) | (k >> 5);
      W1F[(slot << 9) + (lanep << 3) + (k & 7)] = h;
    }
    {
      int k = idx >> 6, col = idx & 63;
      short h = to_bf16(w2[idx]);
      int lanep = (((k >> 3) & 3) << 4) | (col & 15);
      int slot  = ((col >> 4) << 3) | (k >> 5);
      W2F[(slot << 9) + (lanep << 3) + (k & 7)] = h;
    }
  }

  char* const AR = ARENA[wv];
  {
    const float* rowp = outm + (tok0 + (long long)(wv * 64 + l)) * CC;
    float v[CC];
    #pragma unroll
    for (int i = 0; i < 16; ++i) {
      float4 f = ((const float4*)rowp)[i];
      v[4 * i] = f.x; v[4 * i + 1] = f.y; v[4 * i + 2] = f.z; v[4 * i + 3] = f.w;
    }
    float s = 0.0f, s2 = 0.0f;
    #pragma unroll
    for (int i = 0; i < CC; ++i) { s += v[i]; s2 += v[i] * v[i]; }
    float mu  = s * (1.0f / 64.0f);
    float var = fmaxf(s2 * (1.0f / 64.0f) - mu * mu, 0.0f);
    float rs  = rsqrtf(var + 1e-5f);
    #pragma unroll
    for (int c = 0; c < 8; ++c) {
      bf16x8 w;
      #pragma unroll
      for (int j = 0; j < 8; ++j) {
        int ch = c * 8 + j;
        w[j] = to_bf16((v[ch] - mu) * rs * n2g[ch] + n2b[ch]);
      }
      *(bf16x8*)(AR + l * 128 + ((c * 16) ^ ((l & 7) << 4))) = w;
    }
  }
  __syncthreads();

  bf16x8 afa[4][2];
  #pragma unroll
  for (int m = 0; m < 4; ++m) {
    int row = 16 * m + (l & 15);
    #pragma unroll
    for (int s = 0; s < 2; ++s)
      afa[m][s] = *(const bf16x8*)(AR + row * 128 + ((64 * s + ((l >> 4) << 4)) ^ ((row & 7) << 4)));
  }

  f32x4 acc2[4][4];
  #pragma unroll
  for (int n = 0; n < 4; ++n) {
    float bb = b2[16 * n + (l & 15)];
    #pragma unroll
    for (int m = 0; m < 4; ++m) { acc2[m][n][0] = bb; acc2[m][n][1] = bb; acc2[m][n][2] = bb; acc2[m][n][3] = bb; }
  }

  char* const HB = AR + 8192;

  #pragma unroll 1
  for (int g = 0; g < 4; ++g) {
    bf16x8 bf[4][2];
    #pragma unroll
    for (int n = 0; n < 4; ++n)
      #pragma unroll
      for (int s = 0; s < 2; ++s)
        bf[n][s] = *(const bf16x8*)(W1F + ((((g * 4 + n) * 2 + s) << 9) + (l << 3)));
    f32x4 a1[4][4];
    #pragma unroll
    for (int m = 0; m < 4; ++m)
      #pragma unroll
      for (int n = 0; n < 4; ++n) {
        f32x4 z = {0.0f, 0.0f, 0.0f, 0.0f};
        z = __builtin_amdgcn_mfma_f32_16x16x32_bf16(afa[m][0], bf[n][0], z, 0, 0, 0);
        a1[m][n] = __builtin_amdgcn_mfma_f32_16x16x32_bf16(afa[m][1], bf[n][1], z, 0, 0, 0);
      }
    float b1v[4];
    #pragma unroll
    for (int n = 0; n < 4; ++n) b1v[n] = b1[g * 64 + 16 * n + (l & 15)];
    #pragma unroll
    for (int m = 0; m < 4; ++m)
      #pragma unroll
      for (int n = 0; n < 4; ++n)
        #pragma unroll
        for (int r = 0; r < 4; ++r) {
          float u = a1[m][n][r] + b1v[n];
          int row = 16 * m + ((l >> 4) << 2) + r;
          *(short*)(HB + row * 128 + (((16 * n + (l & 15)) << 1) ^ ((row & 7) << 4))) = to_bf16(gelu_tanh(u));
        }
    bf16x8 a2[4][2], b2f[4][2];
    #pragma unroll
    for (int m = 0; m < 4; ++m) {
      int row = 16 * m + (l & 15);
      #pragma unroll
      for (int s = 0; s < 2; ++s)
        a2[m][s] = *(const bf16x8*)(HB + row * 128 + ((64 * s + ((l >> 4) << 4)) ^ ((row & 7) << 4)));
    }
    #pragma unroll
    for (int n = 0; n < 4; ++n)
      #pragma unroll
      for (int s = 0; s < 2; ++s)
        b2f[n][s] = *(const bf16x8*)(W2F + (((n * 8 + g * 2 + s) << 9) + (l << 3)));
    #pragma unroll
    for (int m = 0; m < 4; ++m)
      #pragma unroll
      for (int n = 0; n < 4; ++n) {
        acc2[m][n] = __builtin_amdgcn_mfma_f32_16x16x32_bf16(a2[m][0], b2f[n][0], acc2[m][n], 0, 0, 0);
        acc2[m][n] = __builtin_amdgcn_mfma_f32_16x16x32_bf16(a2[m][1], b2f[n][1], acc2[m][n], 0, 0, 0);
      }
  }

  float* const OF = (float*)AR;
  #pragma unroll
  for (int m = 0; m < 4; ++m)
    #pragma unroll
    for (int n = 0; n < 4; ++n)
      #pragma unroll
      for (int r = 0; r < 4; ++r) {
        int row = 16 * m + ((l >> 4) << 2) + r;
        OF[row * 64 + 16 * n + (l & 15)] = acc2[m][n][r];
      }
  #pragma unroll
  for (int i = 0; i < 16; ++i) {
    int row = i * 4 + (l >> 4);
    f32x4 v4 = *(const f32x4*)(OF + row * 64 + ((l & 15) << 2));
    float* rp = outm + (tok0 + (long long)(wv * 64 + row)) * CC + ((l & 15) << 2);
    float4 g4 = *(const float4*)rp;
    float4 o;
    o.x = g4.x + v4[0]; o.y = g4.y + v4[1]; o.z = g4.z + v4[2]; o.w = g4.w + v4[3];
    *(float4*)rp = o;
  }
}

// ---------------------------------------------------------------------------
extern "C" void kernel_launch(void* const* d_in, const int* in_sizes, int n_in,
                              void* d_out, int out_size, void* d_ws, size_t ws_size,
                              hipStream_t stream) {
  const float* x      = (const float*)d_in[0];
  const float* y      = (const float*)d_in[1];
  const float* n1g    = (const float*)d_in[2];
  const float* n1b    = (const float*)d_in[3];
  const float* qkv_w  = (const float*)d_in[4];
  const float* qkv_b  = (const float*)d_in[5];
  const float* proj_w = (const float*)d_in[6];
  const float* proj_b = (const float*)d_in[7];
  const float* pp_w   = (const float*)d_in[8];
  const float* pp_b   = (const float*)d_in[9];
  const float* ln1g   = (const float*)d_in[10];
  const float* ln1b   = (const float*)d_in[11];
  const float* l1w    = (const float*)d_in[12];
  const float* l1b    = (const float*)d_in[13];
  const float* ln2g   = (const float*)d_in[14];
  const float* ln2b   = (const float*)d_in[15];
  const float* l2w    = (const float*)d_in[16];
  const float* l2b    = (const float*)d_in[17];
  const float* ln3g   = (const float*)d_in[18];
  const float* ln3b   = (const float*)d_in[19];
  const float* l3w    = (const float*)d_in[20];
  const float* l3b    = (const float*)d_in[21];
  const float* n2g    = (const float*)d_in[22];
  const float* n2b    = (const float*)d_in[23];
  const float* fx1w   = (const float*)d_in[24];
  const float* fx1b   = (const float*)d_in[25];
  const float* fx2w   = (const float*)d_in[26];
  const float* fx2b   = (const float*)d_in[27];
  const float* fy1w   = (const float*)d_in[28];
  const float* fy1b   = (const float*)d_in[29];
  const float* fy2w   = (const float*)d_in[30];
  const float* fy2b   = (const float*)d_in[31];
  (void)in_sizes; (void)n_in; (void)out_size; (void)ws_size;

  float* out = (float*)d_out;
  char*  ws  = (char*)d_ws;
  float* p_table  = (float*)(ws + WS_PTAB);
  float* bias_exp = (float*)(ws + WS_BIAS);
  short* wqkvF    = (short*)(ws + WS_WQKV);
  short* projF    = (short*)(ws + WS_WPROJ);

  pbias_kernel<<<1, 512, 0, stream>>>(pp_w, pp_b, ln1g, ln1b, l1w, l1b,
                                      ln2g, ln2b, l2w, l2b, ln3g, ln3b, l3w, l3b, p_table);
  bias_expand_kernel<<<64, 256, 0, stream>>>(p_table, bias_exp);
  prep_w_kernel<<<64, 256, 0, stream>>>(qkv_w, proj_w, wqkvF, projF);
  win_attn_kernel<<<NWIN, 256, 0, stream>>>(x, y, n1g, n1b, qkv_b, proj_b,
                                            bias_exp, wqkvF, projF, out);
  mlp_mfma_kernel<<<1024, 256, 0, stream>>>(n2g, n2b, fx1w, fx1b, fx2w, fx2b,
                                            fy1w, fy1b, fy2w, fy2b, out);
}

// Round 4
// 177.491 us; speedup vs baseline: 21.5630x; 1.2795x over previous
//
#include <hip/hip_runtime.h>
#include <math.h>

constexpr int CC    = 64;          // channels
constexpr int GG    = 8;           // window size
constexpr int H0    = 256;
constexpr int W0c   = 256;
constexpr int BB    = 2;
constexpr int LL    = H0 * W0c;                     // 65536
constexpr int NWIN  = BB * (H0 / GG) * (W0c / GG);  // 2048
constexpr int HIDN  = 256;                          // MLP hidden
constexpr int NBIA  = 31 * 15;                      // 465 relative-pos entries
constexpr long long MODSZ = (long long)BB * LL * CC; // 8388608 floats per modality

// ws byte offsets
constexpr int WS_PTAB  = 0;        // 465*4 f32
constexpr int WS_BIAS  = 8192;     // [4][128][128] f32 = 256 KB
constexpr int WS_WQKV  = 270336;   // 24 slots * 512 bf16 = 24 KB (B-frag image)
constexpr int WS_WPROJ = 294912;   // 8 slots * 512 bf16 = 8 KB
constexpr int WS_MLPW  = 303104;   // 4 images * 16384 bf16 = 128 KB (A-frag images)

using f32x4  = __attribute__((ext_vector_type(4))) float;
using bf16x8 = __attribute__((ext_vector_type(8))) short;
using bf16x4 = __attribute__((ext_vector_type(4))) short;

static __device__ __forceinline__ short to_bf16(float f) {
  unsigned u = __float_as_uint(f);
  unsigned r = (u + 0x7FFFu + ((u >> 16) & 1u)) >> 16;
  return (short)r;
}
static __device__ __forceinline__ float gelu_tanh(float u) {
  float u2 = u * u;
  float t  = fmaf(0.044715f, u2, 1.0f);
  float z  = u * t * 1.5957691216057308f;
  float e  = __expf(-z);
  return u / (1.0f + e);
}

// ---------------------------------------------------------------------------
// Kernel P: dynamic position bias table (465 x 4) via tiny MLP
// ---------------------------------------------------------------------------
static __device__ __forceinline__ void ln4_relu(float* p, const float* g, const float* b) {
  float mu = 0.25f * (p[0] + p[1] + p[2] + p[3]);
  float d0 = p[0] - mu, d1 = p[1] - mu, d2 = p[2] - mu, d3 = p[3] - mu;
  float var = 0.25f * (d0 * d0 + d1 * d1 + d2 * d2 + d3 * d3);
  float rs = rsqrtf(var + 1e-5f);
  p[0] = fmaxf(d0 * rs * g[0] + b[0], 0.0f);
  p[1] = fmaxf(d1 * rs * g[1] + b[1], 0.0f);
  p[2] = fmaxf(d2 * rs * g[2] + b[2], 0.0f);
  p[3] = fmaxf(d3 * rs * g[3] + b[3], 0.0f);
}
static __device__ __forceinline__ void mm4(const float* a, const float* w, const float* b, float* o) {
  #pragma unroll
  for (int j = 0; j < 4; ++j) {
    float s = b[j];
    #pragma unroll
    for (int i = 0; i < 4; ++i) s += a[i] * w[i * 4 + j];
    o[j] = s;
  }
}

__global__ void pbias_kernel(const float* __restrict__ pp_w, const float* __restrict__ pp_b,
                             const float* __restrict__ ln1g, const float* __restrict__ ln1b,
                             const float* __restrict__ l1w,  const float* __restrict__ l1b,
                             const float* __restrict__ ln2g, const float* __restrict__ ln2b,
                             const float* __restrict__ l2w,  const float* __restrict__ l2b,
                             const float* __restrict__ ln3g, const float* __restrict__ ln3b,
                             const float* __restrict__ l3w,  const float* __restrict__ l3b,
                             float* __restrict__ p_table) {
  int r = blockIdx.x * blockDim.x + threadIdx.x;
  if (r >= NBIA) return;
  float bh = (float)(r / 15 - 15);
  float bw = (float)(r % 15 - 7);
  float a[4], t[4];
  #pragma unroll
  for (int j = 0; j < 4; ++j) a[j] = bh * pp_w[j] + bw * pp_w[4 + j] + pp_b[j];
  ln4_relu(a, ln1g, ln1b);
  mm4(a, l1w, l1b, t);
  ln4_relu(t, ln2g, ln2b);
  mm4(t, l2w, l2b, a);
  ln4_relu(a, ln3g, ln3b);
  mm4(a, l3w, l3b, t);
  #pragma unroll
  for (int j = 0; j < 4; ++j) p_table[r * 4 + j] = t[j];
}

// ---------------------------------------------------------------------------
// bias_expand: p_table (465x4) -> dense bias_exp[h][q][k] f32 (4x128x128)
// ---------------------------------------------------------------------------
__global__ void bias_expand_kernel(const float* __restrict__ p_table, float* __restrict__ bias_exp) {
  int gid = blockIdx.x * 256 + threadIdx.x;   // 16384 float4's
  int h   = gid >> 12;
  int rem = gid & 4095;
  int q   = rem >> 5;
  int k0  = (rem & 31) * 4;
  int qih = q >> 3, qiw = q & 7;
  float o[4];
  #pragma unroll
  for (int kk = 0; kk < 4; ++kk) {
    int k = k0 + kk;
    int ridx = (qih - (k >> 3) + 15) * 15 + (qiw - (k & 7) + 7);
    o[kk] = p_table[ridx * 4 + h];
  }
  f32x4 v = {o[0], o[1], o[2], o[3]};
  *(f32x4*)(bias_exp + gid * 4) = v;
}

// ---------------------------------------------------------------------------
// prep_w: qkv_w/proj_w f32 -> bf16 B-fragment images (16x16x32 layout:
// B[k][col]: col=lane&15, k=(lane>>4)*8+j; slot = ntile*2 + kstep).
// q-scale (d^-0.5 = 0.25) folded into q columns.
// ---------------------------------------------------------------------------
__global__ void prep_w_kernel(const float* __restrict__ qkv_w, const float* __restrict__ proj_w,
                              short* __restrict__ wqkvF, short* __restrict__ projF) {
  int t = blockIdx.x * 256 + threadIdx.x;    // 16384
  if (t < 12288) {
    int slot = t >> 9, e = t & 511;
    int lp = e >> 3, j = e & 7;
    int ng = slot >> 1, s = slot & 1;
    int k   = 32 * s + 8 * (lp >> 4) + j;
    int col = 16 * ng + (lp & 15);
    float v = qkv_w[k * 192 + col];
    if (col < 64) v *= 0.25f;
    wqkvF[t] = to_bf16(v);
  } else {
    int t2 = t - 12288;
    int slot = t2 >> 9, e = t2 & 511;
    int lp = e >> 3, j = e & 7;
    int ng = slot >> 1, s = slot & 1;
    int k   = 32 * s + 8 * (lp >> 4) + j;
    int col = 16 * ng + (lp & 15);
    projF[t2] = to_bf16(proj_w[k * 64 + col]);
  }
}

// ---------------------------------------------------------------------------
// prep_mlp_w: fx1w/fy1w/fx2w/fy2w -> bf16 A-fragment images (transposed GEMM).
// A[row][k]: row=lane&15, k=(lane>>4)*8+j.
// img0/1: w1^T (x,y): slot = nt*2+ks (nt=hid tile 0..15, ks=in k-step 0..1):
//   value = w1[in_ch = ks*32+(lp>>4)*8+j][hid = nt*16+(lp&15)]
// img2/3: w2^T (x,y): slot = nt2*8+g2 (nt2=out tile 0..3, g2=hid k-step 0..7):
//   value = w2[hid = g2*32+(lp>>4)*8+j][out = nt2*16+(lp&15)]
// ---------------------------------------------------------------------------
__global__ void prep_mlp_w_kernel(const float* __restrict__ fx1w, const float* __restrict__ fy1w,
                                  const float* __restrict__ fx2w, const float* __restrict__ fy2w,
                                  short* __restrict__ mlpW) {
  int gid = blockIdx.x * 256 + threadIdx.x;   // 65536
  int img = gid >> 14;
  int e   = gid & 16383;
  int slot = e >> 9, lp = (e >> 3) & 63, j = e & 7;
  float v;
  if (img < 2) {
    const float* w1 = img ? fy1w : fx1w;      // (64 x 256)
    int nt = slot >> 1, ks = slot & 1;
    int in_ch = ks * 32 + ((lp >> 4) << 3) + j;
    int hid   = nt * 16 + (lp & 15);
    v = w1[in_ch * HIDN + hid];
  } else {
    const float* w2 = (img & 1) ? fy2w : fx2w; // (256 x 64)
    int nt2 = slot >> 3, g2 = slot & 7;
    int hid = g2 * 32 + ((lp >> 4) << 3) + j;
    int oc  = nt2 * 16 + (lp & 15);
    v = w2[hid * CC + oc];
  }
  mlpW[gid] = to_bf16(v);
}

// ---------------------------------------------------------------------------
// Kernel W v2: all-MFMA fused window attention (unchanged from round 2)
// ---------------------------------------------------------------------------
__launch_bounds__(256, 2)
__global__ void win_attn_kernel(const float* __restrict__ x, const float* __restrict__ y,
                                const float* __restrict__ n1g, const float* __restrict__ n1b,
                                const float* __restrict__ qkv_b, const float* __restrict__ proj_b,
                                const float* __restrict__ bias_exp,
                                const short* __restrict__ wqkvF, const short* __restrict__ projF,
                                float* __restrict__ out) {
  __shared__ __align__(16) char smem[81920];
  char* const TOK_ = smem;            // 16 KB
  char* const QB_  = smem + 16384;    // 16 KB
  char* const KB_  = smem + 32768;    // 16 KB
  char* const VT_  = smem + 49152;    // 16 KB
  char* const PB_  = smem + 65536;    // 16 KB (4 KB per wave)

  const int tid = threadIdx.x;
  const int l   = tid & 63;
  const int l15 = l & 15;
  const int lg  = l >> 4;
  const int wv  = __builtin_amdgcn_readfirstlane(tid >> 6);

  const int widx = blockIdx.x;
  const int b  = widx >> 10;
  const int wl = widx & 1023;
  const int wh = wl >> 5, ww = wl & 31;

  // ---- phase 1: gather + LN -> bf16 A-tile (swizzled) ----
  {
    const int lane16 = tid & 15;
    const float4 g4 = *(const float4*)(n1g + lane16 * 4);
    const float4 b4 = *(const float4*)(n1b + lane16 * 4);
    #pragma unroll
    for (int ps = 0; ps < 8; ++ps) {
      int t  = ps * 16 + (tid >> 4);
      int g  = t & 63;
      const float* src = ((t & 64) ? y : x)
          + ((long long)b * LL + (long long)(wh * GG + (g >> 3)) * W0c + (ww * GG + (g & 7))) * CC
          + lane16 * 4;
      float4 v = *(const float4*)src;
      float s  = v.x + v.y + v.z + v.w;
      float s2 = v.x * v.x + v.y * v.y + v.z * v.z + v.w * v.w;
      #pragma unroll
      for (int m = 1; m < 16; m <<= 1) { s += __shfl_xor(s, m); s2 += __shfl_xor(s2, m); }
      float mu  = s * (1.0f / 64.0f);
      float var = fmaxf(s2 * (1.0f / 64.0f) - mu * mu, 0.0f);
      float rs  = rsqrtf(var + 1e-5f);
      bf16x4 w4 = { to_bf16((v.x - mu) * rs * g4.x + b4.x),
                    to_bf16((v.y - mu) * rs * g4.y + b4.y),
                    to_bf16((v.z - mu) * rs * g4.z + b4.z),
                    to_bf16((v.w - mu) * rs * g4.w + b4.w) };
      *(bf16x4*)(TOK_ + ((t * 128 + lane16 * 8) ^ ((t & 7) << 4))) = w4;
    }
  }
  __syncthreads();

  // ---- phase 2: QKV GEMM (wave owns 48 out channels = 3 N-tiles) ----
  {
    bf16x8 wb[3][2];
    #pragma unroll
    for (int nt = 0; nt < 3; ++nt)
      #pragma unroll
      for (int s = 0; s < 2; ++s)
        wb[nt][s] = *(const bf16x8*)((const char*)wqkvF + (((3 * wv + nt) * 2 + s) << 10) + l * 16);

    f32x4 acc[8][3];
    #pragma unroll
    for (int nt = 0; nt < 3; ++nt) {
      int col = 48 * wv + 16 * nt + l15;
      float bb = qkv_b[col];
      if (col < 64) bb *= 0.25f;
      #pragma unroll
      for (int mt = 0; mt < 8; ++mt) { acc[mt][nt][0] = bb; acc[mt][nt][1] = bb; acc[mt][nt][2] = bb; acc[mt][nt][3] = bb; }
    }
    #pragma unroll
    for (int mt = 0; mt < 8; ++mt) {
      int row = 16 * mt + l15;
      bf16x8 a0 = *(const bf16x8*)(TOK_ + ((row * 128 +      lg * 16) ^ ((row & 7) << 4)));
      bf16x8 a1 = *(const bf16x8*)(TOK_ + ((row * 128 + 64 + lg * 16) ^ ((row & 7) << 4)));
      #pragma unroll
      for (int nt = 0; nt < 3; ++nt) {
        acc[mt][nt] = __builtin_amdgcn_mfma_f32_16x16x32_bf16(a0, wb[nt][0], acc[mt][nt], 0, 0, 0);
        acc[mt][nt] = __builtin_amdgcn_mfma_f32_16x16x32_bf16(a1, wb[nt][1], acc[mt][nt], 0, 0, 0);
      }
    }
    // epilogue: scatter into Q/K [tok][64] or V^T [64][tok] bf16
    #pragma unroll
    for (int nt = 0; nt < 3; ++nt) {
      int cb = 48 * wv + 16 * nt;          // wave-uniform
      int part = cb >> 6;
      int chl = (cb & 63) + l15;
      if (part < 2) {
        char* buf = part ? KB_ : QB_;
        #pragma unroll
        for (int mt = 0; mt < 8; ++mt)
          #pragma unroll
          for (int r = 0; r < 4; ++r) {
            int tok = 16 * mt + lg * 4 + r;
            *(short*)(buf + ((tok * 128 + chl * 2) ^ ((tok & 7) << 4))) = to_bf16(acc[mt][nt][r]);
          }
      } else {
        #pragma unroll
        for (int mt = 0; mt < 8; ++mt) {
          bf16x4 w4 = { to_bf16(acc[mt][nt][0]), to_bf16(acc[mt][nt][1]),
                        to_bf16(acc[mt][nt][2]), to_bf16(acc[mt][nt][3]) };
          int tok0 = 16 * mt + lg * 4;
          *(bf16x4*)(VT_ + ((chl * 256 + tok0 * 2) ^ ((chl & 7) << 4))) = w4;
        }
      }
    }
  }
  __syncthreads();

  // ---- phase 3: attention, wave = head. Swapped QK^T (S^T = K x Q). ----
  {
    const int h = wv;
    const float* biasH = bias_exp + h * 16384;
    bf16x8 kf[8];
    #pragma unroll
    for (int kt = 0; kt < 8; ++kt) {
      bf16x8 f = {0, 0, 0, 0, 0, 0, 0, 0};
      if (l < 32) {
        int row = 16 * kt + l15;
        f = *(const bf16x8*)(KB_ + ((row * 128 + h * 32 + lg * 16) ^ ((row & 7) << 4)));
      }
      kf[kt] = f;
    }
    bf16x8 vf[4];
    #pragma unroll
    for (int ks = 0; ks < 4; ++ks) {
      int row = h * 16 + l15;
      vf[ks] = *(const bf16x8*)(VT_ + ((row * 256 + ks * 64 + lg * 16) ^ ((row & 7) << 4)));
    }
    char* const PBw = PB_ + wv * 4096;

    for (int qt = 0; qt < 8; ++qt) {
      f32x4 bias[8];
      #pragma unroll
      for (int kt = 0; kt < 8; ++kt)
        bias[kt] = *(const f32x4*)(biasH + (16 * qt + l15) * 128 + 16 * kt + 4 * lg);
      bf16x8 qf = {0, 0, 0, 0, 0, 0, 0, 0};
      if (l < 32) {
        int row = 16 * qt + l15;
        qf = *(const bf16x8*)(QB_ + ((row * 128 + h * 32 + lg * 16) ^ ((row & 7) << 4)));
      }
      f32x4 s[8];
      #pragma unroll
      for (int kt = 0; kt < 8; ++kt) {
        f32x4 z = {0.0f, 0.0f, 0.0f, 0.0f};
        s[kt] = __builtin_amdgcn_mfma_f32_16x16x32_bf16(kf[kt], qf, z, 0, 0, 0);
      }
      float m = -1e30f;
      #pragma unroll
      for (int kt = 0; kt < 8; ++kt) {
        s[kt][0] += bias[kt][0]; s[kt][1] += bias[kt][1];
        s[kt][2] += bias[kt][2]; s[kt][3] += bias[kt][3];
        m = fmaxf(m, fmaxf(fmaxf(s[kt][0], s[kt][1]), fmaxf(s[kt][2], s[kt][3])));
      }
      m = fmaxf(m, __shfl_xor(m, 16));
      m = fmaxf(m, __shfl_xor(m, 32));
      float sum = 0.0f;
      #pragma unroll
      for (int kt = 0; kt < 8; ++kt) {
        s[kt][0] = __expf(s[kt][0] - m); s[kt][1] = __expf(s[kt][1] - m);
        s[kt][2] = __expf(s[kt][2] - m); s[kt][3] = __expf(s[kt][3] - m);
        sum += (s[kt][0] + s[kt][1]) + (s[kt][2] + s[kt][3]);
      }
      sum += __shfl_xor(sum, 16);
      sum += __shfl_xor(sum, 32);
      float inv = 1.0f / sum;
      #pragma unroll
      for (int kt = 0; kt < 8; ++kt) {
        bf16x4 pw = { to_bf16(s[kt][0] * inv), to_bf16(s[kt][1] * inv),
                      to_bf16(s[kt][2] * inv), to_bf16(s[kt][3] * inv) };
        int k0 = 16 * kt + 4 * lg;
        *(bf16x4*)(PBw + ((l15 * 256 + k0 * 2) ^ ((l15 & 7) << 4))) = pw;
      }
      f32x4 pacc = {0.0f, 0.0f, 0.0f, 0.0f};
      #pragma unroll
      for (int ks = 0; ks < 4; ++ks) {
        bf16x8 pa = *(const bf16x8*)(PBw + ((l15 * 256 + ks * 64 + lg * 16) ^ ((l15 & 7) << 4)));
        pacc = __builtin_amdgcn_mfma_f32_16x16x32_bf16(pa, vf[ks], pacc, 0, 0, 0);
      }
      #pragma unroll
      for (int r = 0; r < 4; ++r) {
        int tok = 16 * qt + lg * 4 + r;
        *(short*)(TOK_ + ((tok * 128 + (h * 16 + l15) * 2) ^ ((tok & 7) << 4))) = to_bf16(pacc[r]);
      }
    }
  }
  __syncthreads();

  // ---- phase 4: proj (wave owns 16 out channels) + residual ----
  {
    bf16x8 pb[2];
    #pragma unroll
    for (int s = 0; s < 2; ++s)
      pb[s] = *(const bf16x8*)((const char*)projF + (((wv << 1) + s) << 10) + l * 16);
    const int ch = 16 * wv + l15;
    const float bb = proj_b[ch];
    #pragma unroll
    for (int mt = 0; mt < 8; ++mt) {
      int row = 16 * mt + l15;
      bf16x8 a0 = *(const bf16x8*)(TOK_ + ((row * 128 +      lg * 16) ^ ((row & 7) << 4)));
      bf16x8 a1 = *(const bf16x8*)(TOK_ + ((row * 128 + 64 + lg * 16) ^ ((row & 7) << 4)));
      f32x4 acc = {bb, bb, bb, bb};
      acc = __builtin_amdgcn_mfma_f32_16x16x32_bf16(a0, pb[0], acc, 0, 0, 0);
      acc = __builtin_amdgcn_mfma_f32_16x16x32_bf16(a1, pb[1], acc, 0, 0, 0);
      #pragma unroll
      for (int r = 0; r < 4; ++r) {
        int tok = 16 * mt + lg * 4 + r;
        int g   = tok & 63;
        long long base = ((long long)b * LL + (long long)(wh * GG + (g >> 3)) * W0c + (ww * GG + (g & 7))) * CC + ch;
        const float* src = ((tok & 64) ? y : x) + base;
        float* dst = out + ((tok & 64) ? MODSZ : 0) + base;
        *dst = *src + acc[r];
      }
    }
  }
}

// ---------------------------------------------------------------------------
// Kernel M v2: transposed-operand MFMA MLP, zero barriers, pre-formatted
// weights. 2048 blocks x 256 thr (4 waves); wave owns 32 tokens.
// LDS per wave: TOK [32 tok][144B] + HB [32 tok][80B] -> 32 KB per block.
// fc1^T: A=w1T (global image), B=TOK -> D col=token, row=hidden (4 consecutive
// hidden per lane -> b64 hid writes). fc2^T: A=w2T, B=hid^T (b128 reads).
// ---------------------------------------------------------------------------
__launch_bounds__(256, 3)
__global__ void mlp_mfma_kernel(const float* __restrict__ n2g, const float* __restrict__ n2b,
                                const float* __restrict__ fx1b, const float* __restrict__ fx2b,
                                const float* __restrict__ fy1b, const float* __restrict__ fy2b,
                                const short* __restrict__ mlpW, float* __restrict__ out) {
  __shared__ __align__(16) char AR4[4][8192];

  const int tid = threadIdx.x;
  const int l   = tid & 63;
  const int l15 = l & 15;
  const int lg  = l >> 4;
  const int wv  = tid >> 6;
  const int bid = blockIdx.x;
  const int mod = bid >> 10;                         // 0=x, 1=y
  const long long wtok0 = (long long)(bid & 1023) * 128 + wv * 32;

  const float* b1 = mod ? fy1b : fx1b;
  const float* b2 = mod ? fy2b : fx2b;
  const short* w1T = mlpW + mod * 16384;
  const short* w2T = mlpW + 32768 + mod * 16384;
  float* const outm = out + (long long)mod * MODSZ;

  char* const TOKw = AR4[wv];            // 32 rows, stride 144 B
  char* const HBw  = AR4[wv] + 4608;     // 32 rows, stride 80 B

  // ---- LN phase: 16 lanes per token, 4 ch per lane ----
  {
    const f32x4 g4 = *(const f32x4*)(n2g + l15 * 4);
    const f32x4 b4 = *(const f32x4*)(n2b + l15 * 4);
    #pragma unroll
    for (int ps = 0; ps < 8; ++ps) {
      int t = ps * 4 + lg;
      const float* rp = outm + (wtok0 + t) * CC + l15 * 4;
      f32x4 v = *(const f32x4*)rp;
      float s  = v[0] + v[1] + v[2] + v[3];
      float s2 = v[0] * v[0] + v[1] * v[1] + v[2] * v[2] + v[3] * v[3];
      #pragma unroll
      for (int m = 1; m < 16; m <<= 1) { s += __shfl_xor(s, m); s2 += __shfl_xor(s2, m); }
      float mu  = s * (1.0f / 64.0f);
      float var = fmaxf(s2 * (1.0f / 64.0f) - mu * mu, 0.0f);
      float rs  = rsqrtf(var + 1e-5f);
      bf16x4 w4 = { to_bf16((v[0] - mu) * rs * g4[0] + b4[0]),
                    to_bf16((v[1] - mu) * rs * g4[1] + b4[1]),
                    to_bf16((v[2] - mu) * rs * g4[2] + b4[2]),
                    to_bf16((v[3] - mu) * rs * g4[3] + b4[3]) };
      *(bf16x4*)(TOKw + t * 144 + l15 * 8) = w4;
    }
  }
  // per-wave-private LDS: no __syncthreads needed anywhere.

  // ---- token B-frags (col=token, k=in_ch) ----
  bf16x8 tokB[2][2];
  #pragma unroll
  for (int ct = 0; ct < 2; ++ct)
    #pragma unroll
    for (int ks = 0; ks < 2; ++ks)
      tokB[ct][ks] = *(const bf16x8*)(TOKw + (16 * ct + l15) * 144 + ks * 64 + lg * 16);

  // ---- fc2 accumulators (col=token, row=out_ch), bias init ----
  f32x4 acc2[4][2];
  #pragma unroll
  for (int n = 0; n < 4; ++n) {
    f32x4 bb = *(const f32x4*)(b2 + n * 16 + lg * 4);
    acc2[n][0] = bb; acc2[n][1] = bb;
  }

  #pragma unroll 1
  for (int g2 = 0; g2 < 8; ++g2) {
    // fc1 for hidden 32-chunk [g2*32, g2*32+32): two 16-hid tiles
    #pragma unroll
    for (int sub = 0; sub < 2; ++sub) {
      const int nt = g2 * 2 + sub;
      bf16x8 wa0 = *(const bf16x8*)(w1T + ((nt * 2 + 0) << 9) + l * 8);
      bf16x8 wa1 = *(const bf16x8*)(w1T + ((nt * 2 + 1) << 9) + l * 8);
      f32x4 z = {0.0f, 0.0f, 0.0f, 0.0f};
      f32x4 d0 = __builtin_amdgcn_mfma_f32_16x16x32_bf16(wa0, tokB[0][0], z, 0, 0, 0);
      d0 = __builtin_amdgcn_mfma_f32_16x16x32_bf16(wa1, tokB[0][1], d0, 0, 0, 0);
      f32x4 d1 = __builtin_amdgcn_mfma_f32_16x16x32_bf16(wa0, tokB[1][0], z, 0, 0, 0);
      d1 = __builtin_amdgcn_mfma_f32_16x16x32_bf16(wa1, tokB[1][1], d1, 0, 0, 0);
      f32x4 b1v = *(const f32x4*)(b1 + nt * 16 + lg * 4);
      bf16x4 h0, h1;
      #pragma unroll
      for (int r = 0; r < 4; ++r) {
        h0[r] = to_bf16(gelu_tanh(d0[r] + b1v[r]));
        h1[r] = to_bf16(gelu_tanh(d1[r] + b1v[r]));
      }
      *(bf16x4*)(HBw + l15 * 80        + sub * 32 + lg * 8) = h0;
      *(bf16x4*)(HBw + (16 + l15) * 80 + sub * 32 + lg * 8) = h1;
    }
    // fc2 partial: B-frags from HB (k=hid_local, col=token)
    bf16x8 hb0 = *(const bf16x8*)(HBw + l15 * 80        + lg * 16);
    bf16x8 hb1 = *(const bf16x8*)(HBw + (16 + l15) * 80 + lg * 16);
    #pragma unroll
    for (int n = 0; n < 4; ++n) {
      bf16x8 wa = *(const bf16x8*)(w2T + ((n * 8 + g2) << 9) + l * 8);
      acc2[n][0] = __builtin_amdgcn_mfma_f32_16x16x32_bf16(wa, hb0, acc2[n][0], 0, 0, 0);
      acc2[n][1] = __builtin_amdgcn_mfma_f32_16x16x32_bf16(wa, hb1, acc2[n][1], 0, 0, 0);
    }
  }

  // ---- epilogue: residual add, direct float4 stores (4 consecutive ch) ----
  #pragma unroll
  for (int n = 0; n < 4; ++n)
    #pragma unroll
    for (int ct = 0; ct < 2; ++ct) {
      float* rp = outm + (wtok0 + 16 * ct + l15) * CC + n * 16 + lg * 4;
      f32x4 o = *(const f32x4*)rp;
      o[0] += acc2[n][ct][0]; o[1] += acc2[n][ct][1];
      o[2] += acc2[n][ct][2]; o[3] += acc2[n][ct][3];
      *(f32x4*)rp = o;
    }
}

// ---------------------------------------------------------------------------
extern "C" void kernel_launch(void* const* d_in, const int* in_sizes, int n_in,
                              void* d_out, int out_size, void* d_ws, size_t ws_size,
                              hipStream_t stream) {
  const float* x      = (const float*)d_in[0];
  const float* y      = (const float*)d_in[1];
  const float* n1g    = (const float*)d_in[2];
  const float* n1b    = (const float*)d_in[3];
  const float* qkv_w  = (const float*)d_in[4];
  const float* qkv_b  = (const float*)d_in[5];
  const float* proj_w = (const float*)d_in[6];
  const float* proj_b = (const float*)d_in[7];
  const float* pp_w   = (const float*)d_in[8];
  const float* pp_b   = (const float*)d_in[9];
  const float* ln1g   = (const float*)d_in[10];
  const float* ln1b   = (const float*)d_in[11];
  const float* l1w    = (const float*)d_in[12];
  const float* l1b    = (const float*)d_in[13];
  const float* ln2g   = (const float*)d_in[14];
  const float* ln2b   = (const float*)d_in[15];
  const float* l2w    = (const float*)d_in[16];
  const float* l2b    = (const float*)d_in[17];
  const float* ln3g   = (const float*)d_in[18];
  const float* ln3b   = (const float*)d_in[19];
  const float* l3w    = (const float*)d_in[20];
  const float* l3b    = (const float*)d_in[21];
  const float* n2g    = (const float*)d_in[22];
  const float* n2b    = (const float*)d_in[23];
  const float* fx1w   = (const float*)d_in[24];
  const float* fx1b   = (const float*)d_in[25];
  const float* fx2w   = (const float*)d_in[26];
  const float* fx2b   = (const float*)d_in[27];
  const float* fy1w   = (const float*)d_in[28];
  const float* fy1b   = (const float*)d_in[29];
  const float* fy2w   = (const float*)d_in[30];
  const float* fy2b   = (const float*)d_in[31];
  (void)in_sizes; (void)n_in; (void)out_size; (void)ws_size;

  float* out = (float*)d_out;
  char*  ws  = (char*)d_ws;
  float* p_table  = (float*)(ws + WS_PTAB);
  float* bias_exp = (float*)(ws + WS_BIAS);
  short* wqkvF    = (short*)(ws + WS_WQKV);
  short* projF    = (short*)(ws + WS_WPROJ);
  short* mlpW     = (short*)(ws + WS_MLPW);

  pbias_kernel<<<1, 512, 0, stream>>>(pp_w, pp_b, ln1g, ln1b, l1w, l1b,
                                      ln2g, ln2b, l2w, l2b, ln3g, ln3b, l3w, l3b, p_table);
  bias_expand_kernel<<<64, 256, 0, stream>>>(p_table, bias_exp);
  prep_w_kernel<<<64, 256, 0, stream>>>(qkv_w, proj_w, wqkvF, projF);
  prep_mlp_w_kernel<<<256, 256, 0, stream>>>(fx1w, fy1w, fx2w, fy2w, mlpW);
  win_attn_kernel<<<NWIN, 256, 0, stream>>>(x, y, n1g, n1b, qkv_b, proj_b,
                                            bias_exp, wqkvF, projF, out);
  mlp_mfma_kernel<<<2048, 256, 0, stream>>>(n2g, n2b, fx1b, fx2b, fy1b, fy2b,
                                            mlpW, out);
}

// Round 7
// 173.551 us; speedup vs baseline: 22.0525x; 1.0227x over previous
//
#include <hip/hip_runtime.h>
#include <math.h>

constexpr int CC    = 64;          // channels
constexpr int GG    = 8;           // window size
constexpr int H0    = 256;
constexpr int W0c   = 256;
constexpr int BB    = 2;
constexpr int LL    = H0 * W0c;                     // 65536
constexpr int NWIN  = BB * (H0 / GG) * (W0c / GG);  // 2048
constexpr int HIDN  = 256;                          // MLP hidden
constexpr int NBIA  = 31 * 15;                      // 465 relative-pos entries
constexpr long long MODSZ = (long long)BB * LL * CC; // 8388608 floats per modality

// ws byte offsets
constexpr int WS_PTAB  = 0;        // 465*4 f32
constexpr int WS_BIAS  = 8192;     // [4][128][128] f32 = 256 KB
constexpr int WS_WQKV  = 270336;   // 24 slots * 512 bf16 = 24 KB (frag image)
constexpr int WS_WPROJ = 294912;   // 8 slots * 512 bf16 = 8 KB
constexpr int WS_MLPW  = 303104;   // 4 images * 16384 bf16 = 128 KB (A-frag images)

using f32x4  = __attribute__((ext_vector_type(4))) float;
using bf16x8 = __attribute__((ext_vector_type(8))) short;
using bf16x4 = __attribute__((ext_vector_type(4))) short;

static __device__ __forceinline__ short to_bf16(float f) {
  unsigned u = __float_as_uint(f);
  unsigned r = (u + 0x7FFFu + ((u >> 16) & 1u)) >> 16;
  return (short)r;
}
// proven manual RNE packing (round-3 primitive) — NO cvt_pk asm (round 4/5 suspect)
static __device__ __forceinline__ bf16x4 mk4_bf16(float a, float b, float c, float d) {
  bf16x4 r;
  r[0] = to_bf16(a); r[1] = to_bf16(b); r[2] = to_bf16(c); r[3] = to_bf16(d);
  return r;
}
static __device__ __forceinline__ float gelu_tanh(float u) {
  float u2 = u * u;
  float t  = fmaf(0.044715f, u2, 1.0f);
  float z  = u * t * 1.5957691216057308f;
  float e  = __expf(-z);
  return u / (1.0f + e);
}

// ---------------------------------------------------------------------------
// Kernel P: dynamic position bias table (465 x 4) via tiny MLP
// ---------------------------------------------------------------------------
static __device__ __forceinline__ void ln4_relu(float* p, const float* g, const float* b) {
  float mu = 0.25f * (p[0] + p[1] + p[2] + p[3]);
  float d0 = p[0] - mu, d1 = p[1] - mu, d2 = p[2] - mu, d3 = p[3] - mu;
  float var = 0.25f * (d0 * d0 + d1 * d1 + d2 * d2 + d3 * d3);
  float rs = rsqrtf(var + 1e-5f);
  p[0] = fmaxf(d0 * rs * g[0] + b[0], 0.0f);
  p[1] = fmaxf(d1 * rs * g[1] + b[1], 0.0f);
  p[2] = fmaxf(d2 * rs * g[2] + b[2], 0.0f);
  p[3] = fmaxf(d3 * rs * g[3] + b[3], 0.0f);
}
static __device__ __forceinline__ void mm4(const float* a, const float* w, const float* b, float* o) {
  #pragma unroll
  for (int j = 0; j < 4; ++j) {
    float s = b[j];
    #pragma unroll
    for (int i = 0; i < 4; ++i) s += a[i] * w[i * 4 + j];
    o[j] = s;
  }
}

__global__ void pbias_kernel(const float* __restrict__ pp_w, const float* __restrict__ pp_b,
                             const float* __restrict__ ln1g, const float* __restrict__ ln1b,
                             const float* __restrict__ l1w,  const float* __restrict__ l1b,
                             const float* __restrict__ ln2g, const float* __restrict__ ln2b,
                             const float* __restrict__ l2w,  const float* __restrict__ l2b,
                             const float* __restrict__ ln3g, const float* __restrict__ ln3b,
                             const float* __restrict__ l3w,  const float* __restrict__ l3b,
                             float* __restrict__ p_table) {
  int r = blockIdx.x * blockDim.x + threadIdx.x;
  if (r >= NBIA) return;
  float bh = (float)(r / 15 - 15);
  float bw = (float)(r % 15 - 7);
  float a[4], t[4];
  #pragma unroll
  for (int j = 0; j < 4; ++j) a[j] = bh * pp_w[j] + bw * pp_w[4 + j] + pp_b[j];
  ln4_relu(a, ln1g, ln1b);
  mm4(a, l1w, l1b, t);
  ln4_relu(t, ln2g, ln2b);
  mm4(t, l2w, l2b, a);
  ln4_relu(a, ln3g, ln3b);
  mm4(a, l3w, l3b, t);
  #pragma unroll
  for (int j = 0; j < 4; ++j) p_table[r * 4 + j] = t[j];
}

// ---------------------------------------------------------------------------
// bias_expand: p_table (465x4) -> dense bias_exp[h][q][k] f32 (4x128x128)
// ---------------------------------------------------------------------------
__global__ void bias_expand_kernel(const float* __restrict__ p_table, float* __restrict__ bias_exp) {
  int gid = blockIdx.x * 256 + threadIdx.x;   // 16384 float4's
  int h   = gid >> 12;
  int rem = gid & 4095;
  int q   = rem >> 5;
  int k0  = (rem & 31) * 4;
  int qih = q >> 3, qiw = q & 7;
  float o[4];
  #pragma unroll
  for (int kk = 0; kk < 4; ++kk) {
    int k = k0 + kk;
    int ridx = (qih - (k >> 3) + 15) * 15 + (qiw - (k & 7) + 7);
    o[kk] = p_table[ridx * 4 + h];
  }
  f32x4 v = {o[0], o[1], o[2], o[3]};
  *(f32x4*)(bias_exp + gid * 4) = v;
}

// ---------------------------------------------------------------------------
// prep_w: weight frag images. image[slot][lane][j] = w[k = 32*(slot&1) +
// 8*(lane>>4) + j][col = 16*(slot>>1) + (lane&15)].  Serves BOTH as B-frag
// of W (col=lane&15) and A-frag of W^T (row=lane&15). q-scale folded in.
// ---------------------------------------------------------------------------
__global__ void prep_w_kernel(const float* __restrict__ qkv_w, const float* __restrict__ proj_w,
                              short* __restrict__ wqkvF, short* __restrict__ projF) {
  int t = blockIdx.x * 256 + threadIdx.x;    // 16384
  if (t < 12288) {
    int slot = t >> 9, e = t & 511;
    int lp = e >> 3, j = e & 7;
    int ng = slot >> 1, s = slot & 1;
    int k   = 32 * s + 8 * (lp >> 4) + j;
    int col = 16 * ng + (lp & 15);
    float v = qkv_w[k * 192 + col];
    if (col < 64) v *= 0.25f;
    wqkvF[t] = to_bf16(v);
  } else {
    int t2 = t - 12288;
    int slot = t2 >> 9, e = t2 & 511;
    int lp = e >> 3, j = e & 7;
    int ng = slot >> 1, s = slot & 1;
    int k   = 32 * s + 8 * (lp >> 4) + j;
    int col = 16 * ng + (lp & 15);
    projF[t2] = to_bf16(proj_w[k * 64 + col]);
  }
}

// ---------------------------------------------------------------------------
// prep_mlp_w (unchanged)
// ---------------------------------------------------------------------------
__global__ void prep_mlp_w_kernel(const float* __restrict__ fx1w, const float* __restrict__ fy1w,
                                  const float* __restrict__ fx2w, const float* __restrict__ fy2w,
                                  short* __restrict__ mlpW) {
  int gid = blockIdx.x * 256 + threadIdx.x;   // 65536
  int img = gid >> 14;
  int e   = gid & 16383;
  int slot = e >> 9, lp = (e >> 3) & 63, j = e & 7;
  float v;
  if (img < 2) {
    const float* w1 = img ? fy1w : fx1w;      // (64 x 256)
    int nt = slot >> 1, ks = slot & 1;
    int in_ch = ks * 32 + ((lp >> 4) << 3) + j;
    int hid   = nt * 16 + (lp & 15);
    v = w1[in_ch * HIDN + hid];
  } else {
    const float* w2 = (img & 1) ? fy2w : fx2w; // (256 x 64)
    int nt2 = slot >> 3, g2 = slot & 7;
    int hid = g2 * 32 + ((lp >> 4) << 3) + j;
    int oc  = nt2 * 16 + (lp & 15);
    v = w2[hid * CC + oc];
  }
  mlpW[gid] = to_bf16(v);
}

// ---------------------------------------------------------------------------
// Kernel W v3b: round-4 structure, round-3 bf16 packing primitive.
// Q,K,proj TRANSPOSED (A = W^T image, B = TOK); V normal; PV operand-swapped.
// Softmax without max subtraction, deferred normalization.
// ---------------------------------------------------------------------------
__launch_bounds__(256, 2)
__global__ void win_attn_kernel(const float* __restrict__ x, const float* __restrict__ y,
                                const float* __restrict__ n1g, const float* __restrict__ n1b,
                                const float* __restrict__ qkv_b, const float* __restrict__ proj_b,
                                const float* __restrict__ bias_exp,
                                const short* __restrict__ wqkvF, const short* __restrict__ projF,
                                float* __restrict__ out) {
  __shared__ __align__(16) char smem[81920];
  char* const TOK_ = smem;            // 16 KB [128 tok][64 ch] bf16 (LN'd; later attn-out)
  char* const QB_  = smem + 16384;    // 16 KB [128 tok][64 d] bf16
  char* const KB_  = smem + 32768;    // 16 KB [128 tok][64 d] bf16
  char* const VT_  = smem + 49152;    // 16 KB [64 d][128 tok] bf16
  char* const PB_  = smem + 65536;    // 16 KB (4 KB per wave) [16 q][128 k] bf16

  const int tid = threadIdx.x;
  const int l   = tid & 63;
  const int l15 = l & 15;
  const int lg  = l >> 4;
  const int wv  = __builtin_amdgcn_readfirstlane(tid >> 6);

  const int widx = blockIdx.x;
  const int b  = widx >> 10;
  const int wl = widx & 1023;
  const int wh = wl >> 5, ww = wl & 31;

  // ---- phase 1: gather + LN -> bf16 token tile (row-swizzled) ----
  {
    const int lane16 = tid & 15;
    const float4 g4 = *(const float4*)(n1g + lane16 * 4);
    const float4 b4 = *(const float4*)(n1b + lane16 * 4);
    #pragma unroll
    for (int ps = 0; ps < 8; ++ps) {
      int t  = ps * 16 + (tid >> 4);
      int g  = t & 63;
      const float* src = ((t & 64) ? y : x)
          + ((long long)b * LL + (long long)(wh * GG + (g >> 3)) * W0c + (ww * GG + (g & 7))) * CC
          + lane16 * 4;
      float4 v = *(const float4*)src;
      float s  = v.x + v.y + v.z + v.w;
      float s2 = v.x * v.x + v.y * v.y + v.z * v.z + v.w * v.w;
      #pragma unroll
      for (int m = 1; m < 16; m <<= 1) { s += __shfl_xor(s, m); s2 += __shfl_xor(s2, m); }
      float mu  = s * (1.0f / 64.0f);
      float var = fmaxf(s2 * (1.0f / 64.0f) - mu * mu, 0.0f);
      float rs  = rsqrtf(var + 1e-5f);
      bf16x4 w4 = mk4_bf16((v.x - mu) * rs * g4.x + b4.x,
                           (v.y - mu) * rs * g4.y + b4.y,
                           (v.z - mu) * rs * g4.z + b4.z,
                           (v.w - mu) * rs * g4.w + b4.w);
      *(bf16x4*)(TOK_ + ((t * 128 + lane16 * 8) ^ ((t & 7) << 4))) = w4;
    }
  }
  __syncthreads();

  // ---- phase 2: QKV. waves 0,1 -> Q^T (32 ch each); waves 2,3 -> K^T;
  //      every wave also one 16-ch V tile. One TOK read feeds both. ----
  {
    bf16x8 awq[2][2];                   // A-frags of W^T (Q or K half)
    #pragma unroll
    for (int ct = 0; ct < 2; ++ct)
      #pragma unroll
      for (int ks = 0; ks < 2; ++ks)
        awq[ct][ks] = *(const bf16x8*)((const char*)wqkvF + ((((2 * wv + ct) * 2 + ks)) << 10) + l * 16);
    bf16x8 bwv[2];                      // B-frags of W_v tile
    #pragma unroll
    for (int ks = 0; ks < 2; ++ks)
      bwv[ks] = *(const bf16x8*)((const char*)wqkvF + (((8 + wv) * 2 + ks) << 10) + l * 16);

    f32x4 bq[2];
    #pragma unroll
    for (int ct = 0; ct < 2; ++ct) {
      f32x4 bb = *(const f32x4*)(qkv_b + (2 * wv + ct) * 16 + lg * 4);
      if (wv < 2) { bb[0] *= 0.25f; bb[1] *= 0.25f; bb[2] *= 0.25f; bb[3] *= 0.25f; }
      bq[ct] = bb;
    }
    const float bv = qkv_b[128 + wv * 16 + l15];
    char* const QKbuf = (wv < 2) ? QB_ : KB_;
    const int chv = wv * 16 + l15;        // V d-row in VT
    const int vswz = (chv & 7) << 4;

    #pragma unroll
    for (int nt = 0; nt < 8; ++nt) {
      const int row = 16 * nt + l15;
      const int rswz = (row & 7) << 4;
      bf16x8 t0 = *(const bf16x8*)(TOK_ + ((row * 128 +  0 + lg * 16) ^ rswz));
      bf16x8 t1 = *(const bf16x8*)(TOK_ + ((row * 128 + 64 + lg * 16) ^ rswz));
      // Q^T / K^T: D col=token(l15), row=4 consecutive d
      #pragma unroll
      for (int ct = 0; ct < 2; ++ct) {
        f32x4 a = bq[ct];
        a = __builtin_amdgcn_mfma_f32_16x16x32_bf16(awq[ct][0], t0, a, 0, 0, 0);
        a = __builtin_amdgcn_mfma_f32_16x16x32_bf16(awq[ct][1], t1, a, 0, 0, 0);
        int chL = (((2 * wv + ct) * 16) & 63) + lg * 4;
        *(bf16x4*)(QKbuf + ((row * 128 + chL * 2) ^ rswz)) = mk4_bf16(a[0], a[1], a[2], a[3]);
      }
      // V: D col=d(l15), row=4 consecutive tokens -> VT row write
      {
        f32x4 a = {bv, bv, bv, bv};
        a = __builtin_amdgcn_mfma_f32_16x16x32_bf16(t0, bwv[0], a, 0, 0, 0);
        a = __builtin_amdgcn_mfma_f32_16x16x32_bf16(t1, bwv[1], a, 0, 0, 0);
        int tok0 = 16 * nt + lg * 4;
        *(bf16x4*)(VT_ + ((chv * 256 + tok0 * 2) ^ vswz)) = mk4_bf16(a[0], a[1], a[2], a[3]);
      }
    }
  }
  __syncthreads();

  // ---- phase 3: attention, wave = head.  S^T = K x Q (swapped). ----
  {
    const int h = wv;
    const float* biasH = bias_exp + h * 16384;
    bf16x8 kf[8];
    #pragma unroll
    for (int kt = 0; kt < 8; ++kt) {
      bf16x8 f = {0, 0, 0, 0, 0, 0, 0, 0};
      if (l < 32) {
        int row = 16 * kt + l15;
        f = *(const bf16x8*)(KB_ + ((row * 128 + h * 32 + lg * 16) ^ ((row & 7) << 4)));
      }
      kf[kt] = f;
    }
    bf16x8 vf[4];                       // VT rows h*16+l15 (A-frag: row=d, k=tok)
    #pragma unroll
    for (int ks = 0; ks < 4; ++ks) {
      int row = h * 16 + l15;
      vf[ks] = *(const bf16x8*)(VT_ + ((row * 256 + ks * 64 + lg * 16) ^ ((row & 7) << 4)));
    }
    char* const PBw = PB_ + wv * 4096;
    const int pswz = (l15 & 7) << 4;

    for (int qt = 0; qt < 8; ++qt) {
      f32x4 bias[8];
      #pragma unroll
      for (int kt = 0; kt < 8; ++kt)
        bias[kt] = *(const f32x4*)(biasH + (16 * qt + l15) * 128 + 16 * kt + 4 * lg);
      bf16x8 qf = {0, 0, 0, 0, 0, 0, 0, 0};
      if (l < 32) {
        int row = 16 * qt + l15;
        qf = *(const bf16x8*)(QB_ + ((row * 128 + h * 32 + lg * 16) ^ ((row & 7) << 4)));
      }
      f32x4 s[8];
      #pragma unroll
      for (int kt = 0; kt < 8; ++kt) {
        f32x4 z = {0.0f, 0.0f, 0.0f, 0.0f};
        s[kt] = __builtin_amdgcn_mfma_f32_16x16x32_bf16(kf[kt], qf, z, 0, 0, 0);
      }
      // exp(s + bias), no max subtraction (|s+bias| < ~4), deferred norm
      float sum = 0.0f;
      #pragma unroll
      for (int kt = 0; kt < 8; ++kt) {
        s[kt][0] = __expf(s[kt][0] + bias[kt][0]);
        s[kt][1] = __expf(s[kt][1] + bias[kt][1]);
        s[kt][2] = __expf(s[kt][2] + bias[kt][2]);
        s[kt][3] = __expf(s[kt][3] + bias[kt][3]);
        sum += (s[kt][0] + s[kt][1]) + (s[kt][2] + s[kt][3]);
      }
      sum += __shfl_xor(sum, 16);
      sum += __shfl_xor(sum, 32);
      float inv = 1.0f / sum;           // all lanes: inv of q = l15
      // unnormalized P -> PBw [q=l15][k], packed bf16x4 writes
      #pragma unroll
      for (int kt = 0; kt < 8; ++kt) {
        int k0 = 16 * kt + 4 * lg;
        *(bf16x4*)(PBw + ((l15 * 256 + k0 * 2) ^ pswz)) = mk4_bf16(s[kt][0], s[kt][1], s[kt][2], s[kt][3]);
      }
      // PV swapped: A = V-frag, B = P-frag -> D col=q(l15), row=4 consecutive d
      f32x4 pacc = {0.0f, 0.0f, 0.0f, 0.0f};
      #pragma unroll
      for (int ks = 0; ks < 4; ++ks) {
        bf16x8 pa = *(const bf16x8*)(PBw + ((l15 * 256 + ks * 64 + lg * 16) ^ pswz));
        pacc = __builtin_amdgcn_mfma_f32_16x16x32_bf16(vf[ks], pa, pacc, 0, 0, 0);
      }
      pacc[0] *= inv; pacc[1] *= inv; pacc[2] *= inv; pacc[3] *= inv;
      // attn-out: TOK[q=l15][h*16 + lg*4 .. +3], packed bf16x4
      *(bf16x4*)(TOK_ + (((16 * qt + l15) * 128 + (h * 16 + lg * 4) * 2) ^ (((16 * qt + l15) & 7) << 4)))
          = mk4_bf16(pacc[0], pacc[1], pacc[2], pacc[3]);
    }
  }
  __syncthreads();

  // ---- phase 4: proj^T (A = proj_w^T image, B = attn-out) + residual ----
  {
    bf16x8 pa2[2];
    #pragma unroll
    for (int ks = 0; ks < 2; ++ks)
      pa2[ks] = *(const bf16x8*)((const char*)projF + (((wv * 2 + ks)) << 10) + l * 16);
    const f32x4 bp = *(const f32x4*)(proj_b + wv * 16 + lg * 4);
    #pragma unroll
    for (int nt = 0; nt < 8; ++nt) {
      const int row = 16 * nt + l15;       // token
      const int rswz = (row & 7) << 4;
      bf16x8 t0 = *(const bf16x8*)(TOK_ + ((row * 128 +  0 + lg * 16) ^ rswz));
      bf16x8 t1 = *(const bf16x8*)(TOK_ + ((row * 128 + 64 + lg * 16) ^ rswz));
      f32x4 acc = bp;
      acc = __builtin_amdgcn_mfma_f32_16x16x32_bf16(pa2[0], t0, acc, 0, 0, 0);
      acc = __builtin_amdgcn_mfma_f32_16x16x32_bf16(pa2[1], t1, acc, 0, 0, 0);
      // D col=token(l15), row=4 consecutive out-ch -> dwordx4 residual
      int g = row & 63;
      long long base = ((long long)b * LL + (long long)(wh * GG + (g >> 3)) * W0c + (ww * GG + (g & 7))) * CC
                       + wv * 16 + lg * 4;
      const float* src = ((row & 64) ? y : x) + base;
      float* dst = out + ((row & 64) ? MODSZ : 0) + base;
      f32x4 sv = *(const f32x4*)src;
      sv[0] += acc[0]; sv[1] += acc[1]; sv[2] += acc[2]; sv[3] += acc[3];
      *(f32x4*)dst = sv;
    }
  }
}

// ---------------------------------------------------------------------------
// Kernel M v2: transposed-operand MFMA MLP (round-3 exact, to_bf16 packing)
// ---------------------------------------------------------------------------
__launch_bounds__(256, 3)
__global__ void mlp_mfma_kernel(const float* __restrict__ n2g, const float* __restrict__ n2b,
                                const float* __restrict__ fx1b, const float* __restrict__ fx2b,
                                const float* __restrict__ fy1b, const float* __restrict__ fy2b,
                                const short* __restrict__ mlpW, float* __restrict__ out) {
  __shared__ __align__(16) char AR4[4][8192];

  const int tid = threadIdx.x;
  const int l   = tid & 63;
  const int l15 = l & 15;
  const int lg  = l >> 4;
  const int wv  = tid >> 6;
  const int bid = blockIdx.x;
  const int mod = bid >> 10;                         // 0=x, 1=y
  const long long wtok0 = (long long)(bid & 1023) * 128 + wv * 32;

  const float* b1 = mod ? fy1b : fx1b;
  const float* b2 = mod ? fy2b : fx2b;
  const short* w1T = mlpW + mod * 16384;
  const short* w2T = mlpW + 32768 + mod * 16384;
  float* const outm = out + (long long)mod * MODSZ;

  char* const TOKw = AR4[wv];            // 32 rows, stride 144 B
  char* const HBw  = AR4[wv] + 4608;     // 32 rows, stride 80 B

  {
    const f32x4 g4 = *(const f32x4*)(n2g + l15 * 4);
    const f32x4 b4 = *(const f32x4*)(n2b + l15 * 4);
    #pragma unroll
    for (int ps = 0; ps < 8; ++ps) {
      int t = ps * 4 + lg;
      const float* rp = outm + (wtok0 + t) * CC + l15 * 4;
      f32x4 v = *(const f32x4*)rp;
      float s  = v[0] + v[1] + v[2] + v[3];
      float s2 = v[0] * v[0] + v[1] * v[1] + v[2] * v[2] + v[3] * v[3];
      #pragma unroll
      for (int m = 1; m < 16; m <<= 1) { s += __shfl_xor(s, m); s2 += __shfl_xor(s2, m); }
      float mu  = s * (1.0f / 64.0f);
      float var = fmaxf(s2 * (1.0f / 64.0f) - mu * mu, 0.0f);
      float rs  = rsqrtf(var + 1e-5f);
      bf16x4 w4 = mk4_bf16((v[0] - mu) * rs * g4[0] + b4[0],
                           (v[1] - mu) * rs * g4[1] + b4[1],
                           (v[2] - mu) * rs * g4[2] + b4[2],
                           (v[3] - mu) * rs * g4[3] + b4[3]);
      *(bf16x4*)(TOKw + t * 144 + l15 * 8) = w4;
    }
  }

  bf16x8 tokB[2][2];
  #pragma unroll
  for (int ct = 0; ct < 2; ++ct)
    #pragma unroll
    for (int ks = 0; ks < 2; ++ks)
      tokB[ct][ks] = *(const bf16x8*)(TOKw + (16 * ct + l15) * 144 + ks * 64 + lg * 16);

  f32x4 acc2[4][2];
  #pragma unroll
  for (int n = 0; n < 4; ++n) {
    f32x4 bb = *(const f32x4*)(b2 + n * 16 + lg * 4);
    acc2[n][0] = bb; acc2[n][1] = bb;
  }

  #pragma unroll 1
  for (int g2 = 0; g2 < 8; ++g2) {
    #pragma unroll
    for (int sub = 0; sub < 2; ++sub) {
      const int nt = g2 * 2 + sub;
      bf16x8 wa0 = *(const bf16x8*)(w1T + ((nt * 2 + 0) << 9) + l * 8);
      bf16x8 wa1 = *(const bf16x8*)(w1T + ((nt * 2 + 1) << 9) + l * 8);
      f32x4 z = {0.0f, 0.0f, 0.0f, 0.0f};
      f32x4 d0 = __builtin_amdgcn_mfma_f32_16x16x32_bf16(wa0, tokB[0][0], z, 0, 0, 0);
      d0 = __builtin_amdgcn_mfma_f32_16x16x32_bf16(wa1, tokB[0][1], d0, 0, 0, 0);
      f32x4 d1 = __builtin_amdgcn_mfma_f32_16x16x32_bf16(wa0, tokB[1][0], z, 0, 0, 0);
      d1 = __builtin_amdgcn_mfma_f32_16x16x32_bf16(wa1, tokB[1][1], d1, 0, 0, 0);
      f32x4 b1v = *(const f32x4*)(b1 + nt * 16 + lg * 4);
      bf16x4 h0 = mk4_bf16(gelu_tanh(d0[0] + b1v[0]), gelu_tanh(d0[1] + b1v[1]),
                           gelu_tanh(d0[2] + b1v[2]), gelu_tanh(d0[3] + b1v[3]));
      bf16x4 h1 = mk4_bf16(gelu_tanh(d1[0] + b1v[0]), gelu_tanh(d1[1] + b1v[1]),
                           gelu_tanh(d1[2] + b1v[2]), gelu_tanh(d1[3] + b1v[3]));
      *(bf16x4*)(HBw + l15 * 80        + sub * 32 + lg * 8) = h0;
      *(bf16x4*)(HBw + (16 + l15) * 80 + sub * 32 + lg * 8) = h1;
    }
    bf16x8 hb0 = *(const bf16x8*)(HBw + l15 * 80        + lg * 16);
    bf16x8 hb1 = *(const bf16x8*)(HBw + (16 + l15) * 80 + lg * 16);
    #pragma unroll
    for (int n = 0; n < 4; ++n) {
      bf16x8 wa = *(const bf16x8*)(w2T + ((n * 8 + g2) << 9) + l * 8);
      acc2[n][0] = __builtin_amdgcn_mfma_f32_16x16x32_bf16(wa, hb0, acc2[n][0], 0, 0, 0);
      acc2[n][1] = __builtin_amdgcn_mfma_f32_16x16x32_bf16(wa, hb1, acc2[n][1], 0, 0, 0);
    }
  }

  #pragma unroll
  for (int n = 0; n < 4; ++n)
    #pragma unroll
    for (int ct = 0; ct < 2; ++ct) {
      float* rp = outm + (wtok0 + 16 * ct + l15) * CC + n * 16 + lg * 4;
      f32x4 o = *(const f32x4*)rp;
      o[0] += acc2[n][ct][0]; o[1] += acc2[n][ct][1];
      o[2] += acc2[n][ct][2]; o[3] += acc2[n][ct][3];
      *(f32x4*)rp = o;
    }
}

// ---------------------------------------------------------------------------
extern "C" void kernel_launch(void* const* d_in, const int* in_sizes, int n_in,
                              void* d_out, int out_size, void* d_ws, size_t ws_size,
                              hipStream_t stream) {
  const float* x      = (const float*)d_in[0];
  const float* y      = (const float*)d_in[1];
  const float* n1g    = (const float*)d_in[2];
  const float* n1b    = (const float*)d_in[3];
  const float* qkv_w  = (const float*)d_in[4];
  const float* qkv_b  = (const float*)d_in[5];
  const float* proj_w = (const float*)d_in[6];
  const float* proj_b = (const float*)d_in[7];
  const float* pp_w   = (const float*)d_in[8];
  const float* pp_b   = (const float*)d_in[9];
  const float* ln1g   = (const float*)d_in[10];
  const float* ln1b   = (const float*)d_in[11];
  const float* l1w    = (const float*)d_in[12];
  const float* l1b    = (const float*)d_in[13];
  const float* ln2g   = (const float*)d_in[14];
  const float* ln2b   = (const float*)d_in[15];
  const float* l2w    = (const float*)d_in[16];
  const float* l2b    = (const float*)d_in[17];
  const float* ln3g   = (const float*)d_in[18];
  const float* ln3b   = (const float*)d_in[19];
  const float* l3w    = (const float*)d_in[20];
  const float* l3b    = (const float*)d_in[21];
  const float* n2g    = (const float*)d_in[22];
  const float* n2b    = (const float*)d_in[23];
  const float* fx1w   = (const float*)d_in[24];
  const float* fx1b   = (const float*)d_in[25];
  const float* fx2w   = (const float*)d_in[26];
  const float* fx2b   = (const float*)d_in[27];
  const float* fy1w   = (const float*)d_in[28];
  const float* fy1b   = (const float*)d_in[29];
  const float* fy2w   = (const float*)d_in[30];
  const float* fy2b   = (const float*)d_in[31];
  (void)in_sizes; (void)n_in; (void)out_size; (void)ws_size;

  float* out = (float*)d_out;
  char*  ws  = (char*)d_ws;
  float* p_table  = (float*)(ws + WS_PTAB);
  float* bias_exp = (float*)(ws + WS_BIAS);
  short* wqkvF    = (short*)(ws + WS_WQKV);
  short* projF    = (short*)(ws + WS_WPROJ);
  short* mlpW     = (short*)(ws + WS_MLPW);

  pbias_kernel<<<1, 512, 0, stream>>>(pp_w, pp_b, ln1g, ln1b, l1w, l1b,
                                      ln2g, ln2b, l2w, l2b, ln3g, ln3b, l3w, l3b, p_table);
  bias_expand_kernel<<<64, 256, 0, stream>>>(p_table, bias_exp);
  prep_w_kernel<<<64, 256, 0, stream>>>(qkv_w, proj_w, wqkvF, projF);
  prep_mlp_w_kernel<<<256, 256, 0, stream>>>(fx1w, fy1w, fx2w, fy2w, mlpW);
  win_attn_kernel<<<NWIN, 256, 0, stream>>>(x, y, n1g, n1b, qkv_b, proj_b,
                                            bias_exp, wqkvF, projF, out);
  mlp_mfma_kernel<<<2048, 256, 0, stream>>>(n2g, n2b, fx1b, fx2b, fy1b, fy2b,
                                            mlpW, out);
}

// Round 8
// 169.415 us; speedup vs baseline: 22.5909x; 1.0244x over previous
//
#include <hip/hip_runtime.h>
#include <math.h>

constexpr int CC    = 64;          // channels
constexpr int GG    = 8;           // window size
constexpr int H0    = 256;
constexpr int W0c   = 256;
constexpr int BB    = 2;
constexpr int LL    = H0 * W0c;                     // 65536
constexpr int NWIN  = BB * (H0 / GG) * (W0c / GG);  // 2048
constexpr int HIDN  = 256;                          // MLP hidden
constexpr int NBIA  = 31 * 15;                      // 465 relative-pos entries
constexpr long long MODSZ = (long long)BB * LL * CC; // 8388608 floats per modality

constexpr float INV_LN2 = 1.4426950408889634f;

// ws byte offsets
constexpr int WS_PTAB  = 0;        // 465*4 f32
constexpr int WS_BIAS  = 8192;     // [4][128][128] f32 = 256 KB (pre-scaled by 1/ln2)
constexpr int WS_WQKV  = 270336;   // 24 slots * 512 bf16 = 24 KB (frag image)
constexpr int WS_WPROJ = 294912;   // 8 slots * 512 bf16 = 8 KB
constexpr int WS_MLPW  = 303104;   // 4 images * 16384 bf16 = 128 KB (A-frag images)

using f32x4  = __attribute__((ext_vector_type(4))) float;
using bf16x8 = __attribute__((ext_vector_type(8))) short;
using bf16x4 = __attribute__((ext_vector_type(4))) short;

static __device__ __forceinline__ short to_bf16(float f) {   // RNE (prep kernels)
  unsigned u = __float_as_uint(f);
  unsigned r = (u + 0x7FFFu + ((u >> 16) & 1u)) >> 16;
  return (short)r;
}
// hot-path packing: round-half-up, pair-packed in pure C (no asm — round-5 lesson)
static __device__ __forceinline__ bf16x4 mk4_bf16(float a, float b, float c, float d) {
  unsigned p0 = ((__float_as_uint(a) + 0x8000u) >> 16) | ((__float_as_uint(b) + 0x8000u) & 0xFFFF0000u);
  unsigned p1 = ((__float_as_uint(c) + 0x8000u) >> 16) | ((__float_as_uint(d) + 0x8000u) & 0xFFFF0000u);
  bf16x4 r;
  r[0] = (short)(p0 & 0xFFFFu); r[1] = (short)(p0 >> 16);
  r[2] = (short)(p1 & 0xFFFFu); r[3] = (short)(p1 >> 16);
  return r;
}
static __device__ __forceinline__ float gelu_tanh(float u) {
  float u2 = u * u;
  float t  = fmaf(0.044715f, u2, 1.0f);
  float z  = u * t * 1.5957691216057308f;
  float e  = __expf(-z);
  return u / (1.0f + e);
}

// ---------------------------------------------------------------------------
// Kernel P: dynamic position bias table (465 x 4) via tiny MLP
// ---------------------------------------------------------------------------
static __device__ __forceinline__ void ln4_relu(float* p, const float* g, const float* b) {
  float mu = 0.25f * (p[0] + p[1] + p[2] + p[3]);
  float d0 = p[0] - mu, d1 = p[1] - mu, d2 = p[2] - mu, d3 = p[3] - mu;
  float var = 0.25f * (d0 * d0 + d1 * d1 + d2 * d2 + d3 * d3);
  float rs = rsqrtf(var + 1e-5f);
  p[0] = fmaxf(d0 * rs * g[0] + b[0], 0.0f);
  p[1] = fmaxf(d1 * rs * g[1] + b[1], 0.0f);
  p[2] = fmaxf(d2 * rs * g[2] + b[2], 0.0f);
  p[3] = fmaxf(d3 * rs * g[3] + b[3], 0.0f);
}
static __device__ __forceinline__ void mm4(const float* a, const float* w, const float* b, float* o) {
  #pragma unroll
  for (int j = 0; j < 4; ++j) {
    float s = b[j];
    #pragma unroll
    for (int i = 0; i < 4; ++i) s += a[i] * w[i * 4 + j];
    o[j] = s;
  }
}

__global__ void pbias_kernel(const float* __restrict__ pp_w, const float* __restrict__ pp_b,
                             const float* __restrict__ ln1g, const float* __restrict__ ln1b,
                             const float* __restrict__ l1w,  const float* __restrict__ l1b,
                             const float* __restrict__ ln2g, const float* __restrict__ ln2b,
                             const float* __restrict__ l2w,  const float* __restrict__ l2b,
                             const float* __restrict__ ln3g, const float* __restrict__ ln3b,
                             const float* __restrict__ l3w,  const float* __restrict__ l3b,
                             float* __restrict__ p_table) {
  int r = blockIdx.x * blockDim.x + threadIdx.x;
  if (r >= NBIA) return;
  float bh = (float)(r / 15 - 15);
  float bw = (float)(r % 15 - 7);
  float a[4], t[4];
  #pragma unroll
  for (int j = 0; j < 4; ++j) a[j] = bh * pp_w[j] + bw * pp_w[4 + j] + pp_b[j];
  ln4_relu(a, ln1g, ln1b);
  mm4(a, l1w, l1b, t);
  ln4_relu(t, ln2g, ln2b);
  mm4(t, l2w, l2b, a);
  ln4_relu(a, ln3g, ln3b);
  mm4(a, l3w, l3b, t);
  #pragma unroll
  for (int j = 0; j < 4; ++j) p_table[r * 4 + j] = t[j];
}

// ---------------------------------------------------------------------------
// bias_expand: p_table (465x4) -> dense bias_exp[h][q][k] f32, PRE-SCALED by
// 1/ln2 so the kernel's softmax is a single v_exp (exp2) per score.
// ---------------------------------------------------------------------------
__global__ void bias_expand_kernel(const float* __restrict__ p_table, float* __restrict__ bias_exp) {
  int gid = blockIdx.x * 256 + threadIdx.x;   // 16384 float4's
  int h   = gid >> 12;
  int rem = gid & 4095;
  int q   = rem >> 5;
  int k0  = (rem & 31) * 4;
  int qih = q >> 3, qiw = q & 7;
  float o[4];
  #pragma unroll
  for (int kk = 0; kk < 4; ++kk) {
    int k = k0 + kk;
    int ridx = (qih - (k >> 3) + 15) * 15 + (qiw - (k & 7) + 7);
    o[kk] = p_table[ridx * 4 + h] * INV_LN2;
  }
  f32x4 v = {o[0], o[1], o[2], o[3]};
  *(f32x4*)(bias_exp + gid * 4) = v;
}

// ---------------------------------------------------------------------------
// prep_w: weight frag images. image[slot][lane][j] = w[k = 32*(slot&1) +
// 8*(lane>>4) + j][col = 16*(slot>>1) + (lane&15)].  Serves BOTH as B-frag
// of W (col=lane&15) and A-frag of W^T (row=lane&15).
// q columns scaled by d^-0.5 / ln2 (exp2 folding).
// ---------------------------------------------------------------------------
__global__ void prep_w_kernel(const float* __restrict__ qkv_w, const float* __restrict__ proj_w,
                              short* __restrict__ wqkvF, short* __restrict__ projF) {
  int t = blockIdx.x * 256 + threadIdx.x;    // 16384
  if (t < 12288) {
    int slot = t >> 9, e = t & 511;
    int lp = e >> 3, j = e & 7;
    int ng = slot >> 1, s = slot & 1;
    int k   = 32 * s + 8 * (lp >> 4) + j;
    int col = 16 * ng + (lp & 15);
    float v = qkv_w[k * 192 + col];
    if (col < 64) v *= 0.25f * INV_LN2;
    wqkvF[t] = to_bf16(v);
  } else {
    int t2 = t - 12288;
    int slot = t2 >> 9, e = t2 & 511;
    int lp = e >> 3, j = e & 7;
    int ng = slot >> 1, s = slot & 1;
    int k   = 32 * s + 8 * (lp >> 4) + j;
    int col = 16 * ng + (lp & 15);
    projF[t2] = to_bf16(proj_w[k * 64 + col]);
  }
}

// ---------------------------------------------------------------------------
// prep_mlp_w (unchanged)
// ---------------------------------------------------------------------------
__global__ void prep_mlp_w_kernel(const float* __restrict__ fx1w, const float* __restrict__ fy1w,
                                  const float* __restrict__ fx2w, const float* __restrict__ fy2w,
                                  short* __restrict__ mlpW) {
  int gid = blockIdx.x * 256 + threadIdx.x;   // 65536
  int img = gid >> 14;
  int e   = gid & 16383;
  int slot = e >> 9, lp = (e >> 3) & 63, j = e & 7;
  float v;
  if (img < 2) {
    const float* w1 = img ? fy1w : fx1w;      // (64 x 256)
    int nt = slot >> 1, ks = slot & 1;
    int in_ch = ks * 32 + ((lp >> 4) << 3) + j;
    int hid   = nt * 16 + (lp & 15);
    v = w1[in_ch * HIDN + hid];
  } else {
    const float* w2 = (img & 1) ? fy2w : fx2w; // (256 x 64)
    int nt2 = slot >> 3, g2 = slot & 7;
    int hid = g2 * 32 + ((lp >> 4) << 3) + j;
    int oc  = nt2 * 16 + (lp & 15);
    v = w2[hid * CC + oc];
  }
  mlpW[gid] = to_bf16(v);
}

// ---------------------------------------------------------------------------
// Kernel W v3c: round-7 structure + exp2-fold + bias-as-C-init + cheap packing.
// ---------------------------------------------------------------------------
__launch_bounds__(256, 2)
__global__ void win_attn_kernel(const float* __restrict__ x, const float* __restrict__ y,
                                const float* __restrict__ n1g, const float* __restrict__ n1b,
                                const float* __restrict__ qkv_b, const float* __restrict__ proj_b,
                                const float* __restrict__ bias_exp,
                                const short* __restrict__ wqkvF, const short* __restrict__ projF,
                                float* __restrict__ out) {
  __shared__ __align__(16) char smem[81920];
  char* const TOK_ = smem;            // 16 KB [128 tok][64 ch] bf16 (LN'd; later attn-out)
  char* const QB_  = smem + 16384;    // 16 KB [128 tok][64 d] bf16
  char* const KB_  = smem + 32768;    // 16 KB [128 tok][64 d] bf16
  char* const VT_  = smem + 49152;    // 16 KB [64 d][128 tok] bf16
  char* const PB_  = smem + 65536;    // 16 KB (4 KB per wave) [16 q][128 k] bf16

  const int tid = threadIdx.x;
  const int l   = tid & 63;
  const int l15 = l & 15;
  const int lg  = l >> 4;
  const int wv  = __builtin_amdgcn_readfirstlane(tid >> 6);

  const int widx = blockIdx.x;
  const int b  = widx >> 10;
  const int wl = widx & 1023;
  const int wh = wl >> 5, ww = wl & 31;

  // ---- phase 1: gather + LN -> bf16 token tile (row-swizzled) ----
  {
    const int lane16 = tid & 15;
    const float4 g4 = *(const float4*)(n1g + lane16 * 4);
    const float4 b4 = *(const float4*)(n1b + lane16 * 4);
    #pragma unroll
    for (int ps = 0; ps < 8; ++ps) {
      int t  = ps * 16 + (tid >> 4);
      int g  = t & 63;
      const float* src = ((t & 64) ? y : x)
          + ((long long)b * LL + (long long)(wh * GG + (g >> 3)) * W0c + (ww * GG + (g & 7))) * CC
          + lane16 * 4;
      float4 v = *(const float4*)src;
      float s  = v.x + v.y + v.z + v.w;
      float s2 = v.x * v.x + v.y * v.y + v.z * v.z + v.w * v.w;
      #pragma unroll
      for (int m = 1; m < 16; m <<= 1) { s += __shfl_xor(s, m); s2 += __shfl_xor(s2, m); }
      float mu  = s * (1.0f / 64.0f);
      float var = fmaxf(s2 * (1.0f / 64.0f) - mu * mu, 0.0f);
      float rs  = rsqrtf(var + 1e-5f);
      bf16x4 w4 = mk4_bf16((v.x - mu) * rs * g4.x + b4.x,
                           (v.y - mu) * rs * g4.y + b4.y,
                           (v.z - mu) * rs * g4.z + b4.z,
                           (v.w - mu) * rs * g4.w + b4.w);
      *(bf16x4*)(TOK_ + ((t * 128 + lane16 * 8) ^ ((t & 7) << 4))) = w4;
    }
  }
  __syncthreads();

  // ---- phase 2: QKV. waves 0,1 -> Q^T (32 ch each); waves 2,3 -> K^T;
  //      every wave also one 16-ch V tile. One TOK read feeds both. ----
  {
    bf16x8 awq[2][2];                   // A-frags of W^T (Q or K half)
    #pragma unroll
    for (int ct = 0; ct < 2; ++ct)
      #pragma unroll
      for (int ks = 0; ks < 2; ++ks)
        awq[ct][ks] = *(const bf16x8*)((const char*)wqkvF + ((((2 * wv + ct) * 2 + ks)) << 10) + l * 16);
    bf16x8 bwv[2];                      // B-frags of W_v tile
    #pragma unroll
    for (int ks = 0; ks < 2; ++ks)
      bwv[ks] = *(const bf16x8*)((const char*)wqkvF + (((8 + wv) * 2 + ks) << 10) + l * 16);

    f32x4 bq[2];
    #pragma unroll
    for (int ct = 0; ct < 2; ++ct) {
      f32x4 bb = *(const f32x4*)(qkv_b + (2 * wv + ct) * 16 + lg * 4);
      if (wv < 2) {
        const float qs = 0.25f * INV_LN2;
        bb[0] *= qs; bb[1] *= qs; bb[2] *= qs; bb[3] *= qs;
      }
      bq[ct] = bb;
    }
    const float bv = qkv_b[128 + wv * 16 + l15];
    char* const QKbuf = (wv < 2) ? QB_ : KB_;
    const int chv = wv * 16 + l15;        // V d-row in VT
    const int vswz = (chv & 7) << 4;

    #pragma unroll
    for (int nt = 0; nt < 8; ++nt) {
      const int row = 16 * nt + l15;
      const int rswz = (row & 7) << 4;
      bf16x8 t0 = *(const bf16x8*)(TOK_ + ((row * 128 +  0 + lg * 16) ^ rswz));
      bf16x8 t1 = *(const bf16x8*)(TOK_ + ((row * 128 + 64 + lg * 16) ^ rswz));
      // Q^T / K^T: D col=token(l15), row=4 consecutive d
      #pragma unroll
      for (int ct = 0; ct < 2; ++ct) {
        f32x4 a = bq[ct];
        a = __builtin_amdgcn_mfma_f32_16x16x32_bf16(awq[ct][0], t0, a, 0, 0, 0);
        a = __builtin_amdgcn_mfma_f32_16x16x32_bf16(awq[ct][1], t1, a, 0, 0, 0);
        int chL = (((2 * wv + ct) * 16) & 63) + lg * 4;
        *(bf16x4*)(QKbuf + ((row * 128 + chL * 2) ^ rswz)) = mk4_bf16(a[0], a[1], a[2], a[3]);
      }
      // V: D col=d(l15), row=4 consecutive tokens -> VT row write
      {
        f32x4 a = {bv, bv, bv, bv};
        a = __builtin_amdgcn_mfma_f32_16x16x32_bf16(t0, bwv[0], a, 0, 0, 0);
        a = __builtin_amdgcn_mfma_f32_16x16x32_bf16(t1, bwv[1], a, 0, 0, 0);
        int tok0 = 16 * nt + lg * 4;
        *(bf16x4*)(VT_ + ((chv * 256 + tok0 * 2) ^ vswz)) = mk4_bf16(a[0], a[1], a[2], a[3]);
      }
    }
  }
  __syncthreads();

  // ---- phase 3: attention, wave = head.  S^T = K x Q (swapped). ----
  {
    const int h = wv;
    const float* biasH = bias_exp + h * 16384;
    bf16x8 kf[8];
    #pragma unroll
    for (int kt = 0; kt < 8; ++kt) {
      bf16x8 f = {0, 0, 0, 0, 0, 0, 0, 0};
      if (l < 32) {
        int row = 16 * kt + l15;
        f = *(const bf16x8*)(KB_ + ((row * 128 + h * 32 + lg * 16) ^ ((row & 7) << 4)));
      }
      kf[kt] = f;
    }
    bf16x8 vf[4];                       // VT rows h*16+l15 (A-frag: row=d, k=tok)
    #pragma unroll
    for (int ks = 0; ks < 4; ++ks) {
      int row = h * 16 + l15;
      vf[ks] = *(const bf16x8*)(VT_ + ((row * 256 + ks * 64 + lg * 16) ^ ((row & 7) << 4)));
    }
    char* const PBw = PB_ + wv * 4096;
    const int pswz = (l15 & 7) << 4;

    for (int qt = 0; qt < 8; ++qt) {
      f32x4 bias[8];
      #pragma unroll
      for (int kt = 0; kt < 8; ++kt)
        bias[kt] = *(const f32x4*)(biasH + (16 * qt + l15) * 128 + 16 * kt + 4 * lg);
      bf16x8 qf = {0, 0, 0, 0, 0, 0, 0, 0};
      if (l < 32) {
        int row = 16 * qt + l15;
        qf = *(const bf16x8*)(QB_ + ((row * 128 + h * 32 + lg * 16) ^ ((row & 7) << 4)));
      }
      // S^T tile with BIAS as the MFMA C-input (saves 32 adds/qt)
      f32x4 s[8];
      #pragma unroll
      for (int kt = 0; kt < 8; ++kt)
        s[kt] = __builtin_amdgcn_mfma_f32_16x16x32_bf16(kf[kt], qf, bias[kt], 0, 0, 0);
      // exp2 (scores pre-scaled by 1/ln2); no max subtraction; deferred norm
      float sum = 0.0f;
      #pragma unroll
      for (int kt = 0; kt < 8; ++kt) {
        s[kt][0] = __builtin_amdgcn_exp2f(s[kt][0]);
        s[kt][1] = __builtin_amdgcn_exp2f(s[kt][1]);
        s[kt][2] = __builtin_amdgcn_exp2f(s[kt][2]);
        s[kt][3] = __builtin_amdgcn_exp2f(s[kt][3]);
        sum += (s[kt][0] + s[kt][1]) + (s[kt][2] + s[kt][3]);
      }
      sum += __shfl_xor(sum, 16);
      sum += __shfl_xor(sum, 32);
      float inv = 1.0f / sum;           // all lanes: inv of q = l15
      // unnormalized P -> PBw [q=l15][k], packed bf16x4 writes
      #pragma unroll
      for (int kt = 0; kt < 8; ++kt) {
        int k0 = 16 * kt + 4 * lg;
        *(bf16x4*)(PBw + ((l15 * 256 + k0 * 2) ^ pswz)) = mk4_bf16(s[kt][0], s[kt][1], s[kt][2], s[kt][3]);
      }
      // PV swapped: A = V-frag, B = P-frag -> D col=q(l15), row=4 consecutive d
      f32x4 pacc = {0.0f, 0.0f, 0.0f, 0.0f};
      #pragma unroll
      for (int ks = 0; ks < 4; ++ks) {
        bf16x8 pa = *(const bf16x8*)(PBw + ((l15 * 256 + ks * 64 + lg * 16) ^ pswz));
        pacc = __builtin_amdgcn_mfma_f32_16x16x32_bf16(vf[ks], pa, pacc, 0, 0, 0);
      }
      pacc[0] *= inv; pacc[1] *= inv; pacc[2] *= inv; pacc[3] *= inv;
      // attn-out: TOK[q=l15][h*16 + lg*4 .. +3], packed bf16x4
      *(bf16x4*)(TOK_ + (((16 * qt + l15) * 128 + (h * 16 + lg * 4) * 2) ^ (((16 * qt + l15) & 7) << 4)))
          = mk4_bf16(pacc[0], pacc[1], pacc[2], pacc[3]);
    }
  }
  __syncthreads();

  // ---- phase 4: proj^T (A = proj_w^T image, B = attn-out) + residual ----
  {
    bf16x8 pa2[2];
    #pragma unroll
    for (int ks = 0; ks < 2; ++ks)
      pa2[ks] = *(const bf16x8*)((const char*)projF + (((wv * 2 + ks)) << 10) + l * 16);
    const f32x4 bp = *(const f32x4*)(proj_b + wv * 16 + lg * 4);
    #pragma unroll
    for (int nt = 0; nt < 8; ++nt) {
      const int row = 16 * nt + l15;       // token
      const int rswz = (row & 7) << 4;
      bf16x8 t0 = *(const bf16x8*)(TOK_ + ((row * 128 +  0 + lg * 16) ^ rswz));
      bf16x8 t1 = *(const bf16x8*)(TOK_ + ((row * 128 + 64 + lg * 16) ^ rswz));
      f32x4 acc = bp;
      acc = __builtin_amdgcn_mfma_f32_16x16x32_bf16(pa2[0], t0, acc, 0, 0, 0);
      acc = __builtin_amdgcn_mfma_f32_16x16x32_bf16(pa2[1], t1, acc, 0, 0, 0);
      // D col=token(l15), row=4 consecutive out-ch -> dwordx4 residual
      int g = row & 63;
      long long base = ((long long)b * LL + (long long)(wh * GG + (g >> 3)) * W0c + (ww * GG + (g & 7))) * CC
                       + wv * 16 + lg * 4;
      const float* src = ((row & 64) ? y : x) + base;
      float* dst = out + ((row & 64) ? MODSZ : 0) + base;
      f32x4 sv = *(const f32x4*)src;
      sv[0] += acc[0]; sv[1] += acc[1]; sv[2] += acc[2]; sv[3] += acc[3];
      *(f32x4*)dst = sv;
    }
  }
}

// ---------------------------------------------------------------------------
// Kernel M v2: transposed-operand MFMA MLP (cheap packing)
// ---------------------------------------------------------------------------
__launch_bounds__(256, 3)
__global__ void mlp_mfma_kernel(const float* __restrict__ n2g, const float* __restrict__ n2b,
                                const float* __restrict__ fx1b, const float* __restrict__ fx2b,
                                const float* __restrict__ fy1b, const float* __restrict__ fy2b,
                                const short* __restrict__ mlpW, float* __restrict__ out) {
  __shared__ __align__(16) char AR4[4][8192];

  const int tid = threadIdx.x;
  const int l   = tid & 63;
  const int l15 = l & 15;
  const int lg  = l >> 4;
  const int wv  = tid >> 6;
  const int bid = blockIdx.x;
  const int mod = bid >> 10;                         // 0=x, 1=y
  const long long wtok0 = (long long)(bid & 1023) * 128 + wv * 32;

  const float* b1 = mod ? fy1b : fx1b;
  const float* b2 = mod ? fy2b : fx2b;
  const short* w1T = mlpW + mod * 16384;
  const short* w2T = mlpW + 32768 + mod * 16384;
  float* const outm = out + (long long)mod * MODSZ;

  char* const TOKw = AR4[wv];            // 32 rows, stride 144 B
  char* const HBw  = AR4[wv] + 4608;     // 32 rows, stride 80 B

  {
    const f32x4 g4 = *(const f32x4*)(n2g + l15 * 4);
    const f32x4 b4 = *(const f32x4*)(n2b + l15 * 4);
    #pragma unroll
    for (int ps = 0; ps < 8; ++ps) {
      int t = ps * 4 + lg;
      const float* rp = outm + (wtok0 + t) * CC + l15 * 4;
      f32x4 v = *(const f32x4*)rp;
      float s  = v[0] + v[1] + v[2] + v[3];
      float s2 = v[0] * v[0] + v[1] * v[1] + v[2] * v[2] + v[3] * v[3];
      #pragma unroll
      for (int m = 1; m < 16; m <<= 1) { s += __shfl_xor(s, m); s2 += __shfl_xor(s2, m); }
      float mu  = s * (1.0f / 64.0f);
      float var = fmaxf(s2 * (1.0f / 64.0f) - mu * mu, 0.0f);
      float rs  = rsqrtf(var + 1e-5f);
      bf16x4 w4 = mk4_bf16((v[0] - mu) * rs * g4[0] + b4[0],
                           (v[1] - mu) * rs * g4[1] + b4[1],
                           (v[2] - mu) * rs * g4[2] + b4[2],
                           (v[3] - mu) * rs * g4[3] + b4[3]);
      *(bf16x4*)(TOKw + t * 144 + l15 * 8) = w4;
    }
  }

  bf16x8 tokB[2][2];
  #pragma unroll
  for (int ct = 0; ct < 2; ++ct)
    #pragma unroll
    for (int ks = 0; ks < 2; ++ks)
      tokB[ct][ks] = *(const bf16x8*)(TOKw + (16 * ct + l15) * 144 + ks * 64 + lg * 16);

  f32x4 acc2[4][2];
  #pragma unroll
  for (int n = 0; n < 4; ++n) {
    f32x4 bb = *(const f32x4*)(b2 + n * 16 + lg * 4);
    acc2[n][0] = bb; acc2[n][1] = bb;
  }

  #pragma unroll 1
  for (int g2 = 0; g2 < 8; ++g2) {
    #pragma unroll
    for (int sub = 0; sub < 2; ++sub) {
      const int nt = g2 * 2 + sub;
      bf16x8 wa0 = *(const bf16x8*)(w1T + ((nt * 2 + 0) << 9) + l * 8);
      bf16x8 wa1 = *(const bf16x8*)(w1T + ((nt * 2 + 1) << 9) + l * 8);
      f32x4 z = {0.0f, 0.0f, 0.0f, 0.0f};
      f32x4 d0 = __builtin_amdgcn_mfma_f32_16x16x32_bf16(wa0, tokB[0][0], z, 0, 0, 0);
      d0 = __builtin_amdgcn_mfma_f32_16x16x32_bf16(wa1, tokB[0][1], d0, 0, 0, 0);
      f32x4 d1 = __builtin_amdgcn_mfma_f32_16x16x32_bf16(wa0, tokB[1][0], z, 0, 0, 0);
      d1 = __builtin_amdgcn_mfma_f32_16x16x32_bf16(wa1, tokB[1][1], d1, 0, 0, 0);
      f32x4 b1v = *(const f32x4*)(b1 + nt * 16 + lg * 4);
      bf16x4 h0 = mk4_bf16(gelu_tanh(d0[0] + b1v[0]), gelu_tanh(d0[1] + b1v[1]),
                           gelu_tanh(d0[2] + b1v[2]), gelu_tanh(d0[3] + b1v[3]));
      bf16x4 h1 = mk4_bf16(gelu_tanh(d1[0] + b1v[0]), gelu_tanh(d1[1] + b1v[1]),
                           gelu_tanh(d1[2] + b1v[2]), gelu_tanh(d1[3] + b1v[3]));
      *(bf16x4*)(HBw + l15 * 80        + sub * 32 + lg * 8) = h0;
      *(bf16x4*)(HBw + (16 + l15) * 80 + sub * 32 + lg * 8) = h1;
    }
    bf16x8 hb0 = *(const bf16x8*)(HBw + l15 * 80        + lg * 16);
    bf16x8 hb1 = *(const bf16x8*)(HBw + (16 + l15) * 80 + lg * 16);
    #pragma unroll
    for (int n = 0; n < 4; ++n) {
      bf16x8 wa = *(const bf16x8*)(w2T + ((n * 8 + g2) << 9) + l * 8);
      acc2[n][0] = __builtin_amdgcn_mfma_f32_16x16x32_bf16(wa, hb0, acc2[n][0], 0, 0, 0);
      acc2[n][1] = __builtin_amdgcn_mfma_f32_16x16x32_bf16(wa, hb1, acc2[n][1], 0, 0, 0);
    }
  }

  #pragma unroll
  for (int n = 0; n < 4; ++n)
    #pragma unroll
    for (int ct = 0; ct < 2; ++ct) {
      float* rp = outm + (wtok0 + 16 * ct + l15) * CC + n * 16 + lg * 4;
      f32x4 o = *(const f32x4*)rp;
      o[0] += acc2[n][ct][0]; o[1] += acc2[n][ct][1];
      o[2] += acc2[n][ct][2]; o[3] += acc2[n][ct][3];
      *(f32x4*)rp = o;
    }
}

// ---------------------------------------------------------------------------
extern "C" void kernel_launch(void* const* d_in, const int* in_sizes, int n_in,
                              void* d_out, int out_size, void* d_ws, size_t ws_size,
                              hipStream_t stream) {
  const float* x      = (const float*)d_in[0];
  const float* y      = (const float*)d_in[1];
  const float* n1g    = (const float*)d_in[2];
  const float* n1b    = (const float*)d_in[3];
  const float* qkv_w  = (const float*)d_in[4];
  const float* qkv_b  = (const float*)d_in[5];
  const float* proj_w = (const float*)d_in[6];
  const float* proj_b = (const float*)d_in[7];
  const float* pp_w   = (const float*)d_in[8];
  const float* pp_b   = (const float*)d_in[9];
  const float* ln1g   = (const float*)d_in[10];
  const float* ln1b   = (const float*)d_in[11];
  const float* l1w    = (const float*)d_in[12];
  const float* l1b    = (const float*)d_in[13];
  const float* ln2g   = (const float*)d_in[14];
  const float* ln2b   = (const float*)d_in[15];
  const float* l2w    = (const float*)d_in[16];
  const float* l2b    = (const float*)d_in[17];
  const float* ln3g   = (const float*)d_in[18];
  const float* ln3b   = (const float*)d_in[19];
  const float* l3w    = (const float*)d_in[20];
  const float* l3b    = (const float*)d_in[21];
  const float* n2g    = (const float*)d_in[22];
  const float* n2b    = (const float*)d_in[23];
  const float* fx1w   = (const float*)d_in[24];
  const float* fx1b   = (const float*)d_in[25];
  const float* fx2w   = (const float*)d_in[26];
  const float* fx2b   = (const float*)d_in[27];
  const float* fy1w   = (const float*)d_in[28];
  const float* fy1b   = (const float*)d_in[29];
  const float* fy2w   = (const float*)d_in[30];
  const float* fy2b   = (const float*)d_in[31];
  (void)in_sizes; (void)n_in; (void)out_size; (void)ws_size;

  float* out = (float*)d_out;
  char*  ws  = (char*)d_ws;
  float* p_table  = (float*)(ws + WS_PTAB);
  float* bias_exp = (float*)(ws + WS_BIAS);
  short* wqkvF    = (short*)(ws + WS_WQKV);
  short* projF    = (short*)(ws + WS_WPROJ);
  short* mlpW     = (short*)(ws + WS_MLPW);

  pbias_kernel<<<1, 512, 0, stream>>>(pp_w, pp_b, ln1g, ln1b, l1w, l1b,
                                      ln2g, ln2b, l2w, l2b, ln3g, ln3b, l3w, l3b, p_table);
  bias_expand_kernel<<<64, 256, 0, stream>>>(p_table, bias_exp);
  prep_w_kernel<<<64, 256, 0, stream>>>(qkv_w, proj_w, wqkvF, projF);
  prep_mlp_w_kernel<<<256, 256, 0, stream>>>(fx1w, fy1w, fx2w, fy2w, mlpW);
  win_attn_kernel<<<NWIN, 256, 0, stream>>>(x, y, n1g, n1b, qkv_b, proj_b,
                                            bias_exp, wqkvF, projF, out);
  mlp_mfma_kernel<<<2048, 256, 0, stream>>>(n2g, n2b, fx1b, fx2b, fy1b, fy2b,
                                            mlpW, out);
}

// Round 9
// 168.908 us; speedup vs baseline: 22.6587x; 1.0030x over previous
//
#include <hip/hip_runtime.h>
#include <math.h>

constexpr int CC    = 64;          // channels
constexpr int GG    = 8;           // window size
constexpr int H0    = 256;
constexpr int W0c   = 256;
constexpr int BB    = 2;
constexpr int LL    = H0 * W0c;                     // 65536
constexpr int NWIN  = BB * (H0 / GG) * (W0c / GG);  // 2048
constexpr int HIDN  = 256;                          // MLP hidden
constexpr int NBIA  = 31 * 15;                      // 465 relative-pos entries
constexpr long long MODSZ = (long long)BB * LL * CC; // 8388608 floats per modality

constexpr float INV_LN2 = 1.4426950408889634f;

// ws byte offsets
constexpr int WS_PTAB  = 0;        // 465*4 f32
constexpr int WS_BIAS  = 8192;     // [4][128][128] f32 = 256 KB (pre-scaled by 1/ln2)
constexpr int WS_WQKV  = 270336;   // 24 slots * 512 bf16 = 24 KB (frag image)
constexpr int WS_WPROJ = 294912;   // 8 slots * 512 bf16 = 8 KB
constexpr int WS_MLPW  = 303104;   // 4 images * 16384 bf16 = 128 KB (A-frag images)

using f32x4  = __attribute__((ext_vector_type(4))) float;
using bf16x8 = __attribute__((ext_vector_type(8))) short;
using bf16x4 = __attribute__((ext_vector_type(4))) short;

static __device__ __forceinline__ short to_bf16(float f) {   // RNE (prep kernels)
  unsigned u = __float_as_uint(f);
  unsigned r = (u + 0x7FFFu + ((u >> 16) & 1u)) >> 16;
  return (short)r;
}
// hot-path packing: round-half-up, pair-packed in pure C (no asm — round-5 lesson)
static __device__ __forceinline__ bf16x4 mk4_bf16(float a, float b, float c, float d) {
  unsigned p0 = ((__float_as_uint(a) + 0x8000u) >> 16) | ((__float_as_uint(b) + 0x8000u) & 0xFFFF0000u);
  unsigned p1 = ((__float_as_uint(c) + 0x8000u) >> 16) | ((__float_as_uint(d) + 0x8000u) & 0xFFFF0000u);
  bf16x4 r;
  r[0] = (short)(p0 & 0xFFFFu); r[1] = (short)(p0 >> 16);
  r[2] = (short)(p1 & 0xFFFFu); r[3] = (short)(p1 >> 16);
  return r;
}
static __device__ __forceinline__ float gelu_tanh(float u) {
  float u2 = u * u;
  float t  = fmaf(0.044715f, u2, 1.0f);
  float z  = u * t * 1.5957691216057308f;
  float e  = __expf(-z);
  return u / (1.0f + e);
}

// ---------------------------------------------------------------------------
// Kernel P: dynamic position bias table (465 x 4) via tiny MLP
// ---------------------------------------------------------------------------
static __device__ __forceinline__ void ln4_relu(float* p, const float* g, const float* b) {
  float mu = 0.25f * (p[0] + p[1] + p[2] + p[3]);
  float d0 = p[0] - mu, d1 = p[1] - mu, d2 = p[2] - mu, d3 = p[3] - mu;
  float var = 0.25f * (d0 * d0 + d1 * d1 + d2 * d2 + d3 * d3);
  float rs = rsqrtf(var + 1e-5f);
  p[0] = fmaxf(d0 * rs * g[0] + b[0], 0.0f);
  p[1] = fmaxf(d1 * rs * g[1] + b[1], 0.0f);
  p[2] = fmaxf(d2 * rs * g[2] + b[2], 0.0f);
  p[3] = fmaxf(d3 * rs * g[3] + b[3], 0.0f);
}
static __device__ __forceinline__ void mm4(const float* a, const float* w, const float* b, float* o) {
  #pragma unroll
  for (int j = 0; j < 4; ++j) {
    float s = b[j];
    #pragma unroll
    for (int i = 0; i < 4; ++i) s += a[i] * w[i * 4 + j];
    o[j] = s;
  }
}

__global__ void pbias_kernel(const float* __restrict__ pp_w, const float* __restrict__ pp_b,
                             const float* __restrict__ ln1g, const float* __restrict__ ln1b,
                             const float* __restrict__ l1w,  const float* __restrict__ l1b,
                             const float* __restrict__ ln2g, const float* __restrict__ ln2b,
                             const float* __restrict__ l2w,  const float* __restrict__ l2b,
                             const float* __restrict__ ln3g, const float* __restrict__ ln3b,
                             const float* __restrict__ l3w,  const float* __restrict__ l3b,
                             float* __restrict__ p_table) {
  int r = blockIdx.x * blockDim.x + threadIdx.x;
  if (r >= NBIA) return;
  float bh = (float)(r / 15 - 15);
  float bw = (float)(r % 15 - 7);
  float a[4], t[4];
  #pragma unroll
  for (int j = 0; j < 4; ++j) a[j] = bh * pp_w[j] + bw * pp_w[4 + j] + pp_b[j];
  ln4_relu(a, ln1g, ln1b);
  mm4(a, l1w, l1b, t);
  ln4_relu(t, ln2g, ln2b);
  mm4(t, l2w, l2b, a);
  ln4_relu(a, ln3g, ln3b);
  mm4(a, l3w, l3b, t);
  #pragma unroll
  for (int j = 0; j < 4; ++j) p_table[r * 4 + j] = t[j];
}

// ---------------------------------------------------------------------------
// bias_expand: p_table (465x4) -> dense bias_exp[h][q][k] f32, PRE-SCALED by
// 1/ln2 so the kernel's softmax is a single v_exp (exp2) per score.
// ---------------------------------------------------------------------------
__global__ void bias_expand_kernel(const float* __restrict__ p_table, float* __restrict__ bias_exp) {
  int gid = blockIdx.x * 256 + threadIdx.x;   // 16384 float4's
  int h   = gid >> 12;
  int rem = gid & 4095;
  int q   = rem >> 5;
  int k0  = (rem & 31) * 4;
  int qih = q >> 3, qiw = q & 7;
  float o[4];
  #pragma unroll
  for (int kk = 0; kk < 4; ++kk) {
    int k = k0 + kk;
    int ridx = (qih - (k >> 3) + 15) * 15 + (qiw - (k & 7) + 7);
    o[kk] = p_table[ridx * 4 + h] * INV_LN2;
  }
  f32x4 v = {o[0], o[1], o[2], o[3]};
  *(f32x4*)(bias_exp + gid * 4) = v;
}

// ---------------------------------------------------------------------------
// prep_w: weight frag images. image[slot][lane][j] = w[k = 32*(slot&1) +
// 8*(lane>>4) + j][col = 16*(slot>>1) + (lane&15)].  Serves BOTH as B-frag
// of W (col=lane&15) and A-frag of W^T (row=lane&15).
// q columns scaled by d^-0.5 / ln2 (exp2 folding).
// ---------------------------------------------------------------------------
__global__ void prep_w_kernel(const float* __restrict__ qkv_w, const float* __restrict__ proj_w,
                              short* __restrict__ wqkvF, short* __restrict__ projF) {
  int t = blockIdx.x * 256 + threadIdx.x;    // 16384
  if (t < 12288) {
    int slot = t >> 9, e = t & 511;
    int lp = e >> 3, j = e & 7;
    int ng = slot >> 1, s = slot & 1;
    int k   = 32 * s + 8 * (lp >> 4) + j;
    int col = 16 * ng + (lp & 15);
    float v = qkv_w[k * 192 + col];
    if (col < 64) v *= 0.25f * INV_LN2;
    wqkvF[t] = to_bf16(v);
  } else {
    int t2 = t - 12288;
    int slot = t2 >> 9, e = t2 & 511;
    int lp = e >> 3, j = e & 7;
    int ng = slot >> 1, s = slot & 1;
    int k   = 32 * s + 8 * (lp >> 4) + j;
    int col = 16 * ng + (lp & 15);
    projF[t2] = to_bf16(proj_w[k * 64 + col]);
  }
}

// ---------------------------------------------------------------------------
// prep_mlp_w (unchanged)
// ---------------------------------------------------------------------------
__global__ void prep_mlp_w_kernel(const float* __restrict__ fx1w, const float* __restrict__ fy1w,
                                  const float* __restrict__ fx2w, const float* __restrict__ fy2w,
                                  short* __restrict__ mlpW) {
  int gid = blockIdx.x * 256 + threadIdx.x;   // 65536
  int img = gid >> 14;
  int e   = gid & 16383;
  int slot = e >> 9, lp = (e >> 3) & 63, j = e & 7;
  float v;
  if (img < 2) {
    const float* w1 = img ? fy1w : fx1w;      // (64 x 256)
    int nt = slot >> 1, ks = slot & 1;
    int in_ch = ks * 32 + ((lp >> 4) << 3) + j;
    int hid   = nt * 16 + (lp & 15);
    v = w1[in_ch * HIDN + hid];
  } else {
    const float* w2 = (img & 1) ? fy2w : fx2w; // (256 x 64)
    int nt2 = slot >> 3, g2 = slot & 7;
    int hid = g2 * 32 + ((lp >> 4) << 3) + j;
    int oc  = nt2 * 16 + (lp & 15);
    v = w2[hid * CC + oc];
  }
  mlpW[gid] = to_bf16(v);
}

// ---------------------------------------------------------------------------
// Kernel W v3d: round-8 structure + 2-stage qt pipeline (bias/qf prefetched
// one iteration ahead into named even/odd register sets).
// ---------------------------------------------------------------------------

#define ATT_LOADB(biasreg, qt) { \
  _Pragma("unroll") \
  for (int kt_ = 0; kt_ < 8; ++kt_) \
    biasreg[kt_] = *(const f32x4*)(biasH + (16 * (qt) + l15) * 128 + 16 * kt_ + 4 * lg); }

#define ATT_LOADQ(qfreg, qt) { \
  qfreg = (bf16x8){0, 0, 0, 0, 0, 0, 0, 0}; \
  if (l < 32) { \
    int row_ = 16 * (qt) + l15; \
    qfreg = *(const bf16x8*)(QB_ + ((row_ * 128 + h * 32 + lg * 16) ^ ((row_ & 7) << 4))); } }

#define ATT_BODY(qt, biasreg, qfreg) { \
  f32x4 s_[8]; \
  _Pragma("unroll") \
  for (int kt_ = 0; kt_ < 8; ++kt_) \
    s_[kt_] = __builtin_amdgcn_mfma_f32_16x16x32_bf16(kf[kt_], qfreg, biasreg[kt_], 0, 0, 0); \
  float sum_ = 0.0f; \
  _Pragma("unroll") \
  for (int kt_ = 0; kt_ < 8; ++kt_) { \
    s_[kt_][0] = __builtin_amdgcn_exp2f(s_[kt_][0]); \
    s_[kt_][1] = __builtin_amdgcn_exp2f(s_[kt_][1]); \
    s_[kt_][2] = __builtin_amdgcn_exp2f(s_[kt_][2]); \
    s_[kt_][3] = __builtin_amdgcn_exp2f(s_[kt_][3]); \
    sum_ += (s_[kt_][0] + s_[kt_][1]) + (s_[kt_][2] + s_[kt_][3]); } \
  sum_ += __shfl_xor(sum_, 16); \
  sum_ += __shfl_xor(sum_, 32); \
  float inv_ = 1.0f / sum_; \
  _Pragma("unroll") \
  for (int kt_ = 0; kt_ < 8; ++kt_) { \
    int k0_ = 16 * kt_ + 4 * lg; \
    *(bf16x4*)(PBw + ((l15 * 256 + k0_ * 2) ^ pswz)) = mk4_bf16(s_[kt_][0], s_[kt_][1], s_[kt_][2], s_[kt_][3]); } \
  f32x4 pacc_ = {0.0f, 0.0f, 0.0f, 0.0f}; \
  _Pragma("unroll") \
  for (int ks_ = 0; ks_ < 4; ++ks_) { \
    bf16x8 pa_ = *(const bf16x8*)(PBw + ((l15 * 256 + ks_ * 64 + lg * 16) ^ pswz)); \
    pacc_ = __builtin_amdgcn_mfma_f32_16x16x32_bf16(vf[ks_], pa_, pacc_, 0, 0, 0); } \
  pacc_[0] *= inv_; pacc_[1] *= inv_; pacc_[2] *= inv_; pacc_[3] *= inv_; \
  *(bf16x4*)(TOK_ + (((16 * (qt) + l15) * 128 + (h * 16 + lg * 4) * 2) ^ (((16 * (qt) + l15) & 7) << 4))) \
      = mk4_bf16(pacc_[0], pacc_[1], pacc_[2], pacc_[3]); }

__launch_bounds__(256, 2)
__global__ void win_attn_kernel(const float* __restrict__ x, const float* __restrict__ y,
                                const float* __restrict__ n1g, const float* __restrict__ n1b,
                                const float* __restrict__ qkv_b, const float* __restrict__ proj_b,
                                const float* __restrict__ bias_exp,
                                const short* __restrict__ wqkvF, const short* __restrict__ projF,
                                float* __restrict__ out) {
  __shared__ __align__(16) char smem[81920];
  char* const TOK_ = smem;            // 16 KB [128 tok][64 ch] bf16 (LN'd; later attn-out)
  char* const QB_  = smem + 16384;    // 16 KB [128 tok][64 d] bf16
  char* const KB_  = smem + 32768;    // 16 KB [128 tok][64 d] bf16
  char* const VT_  = smem + 49152;    // 16 KB [64 d][128 tok] bf16
  char* const PB_  = smem + 65536;    // 16 KB (4 KB per wave) [16 q][128 k] bf16

  const int tid = threadIdx.x;
  const int l   = tid & 63;
  const int l15 = l & 15;
  const int lg  = l >> 4;
  const int wv  = __builtin_amdgcn_readfirstlane(tid >> 6);

  const int widx = blockIdx.x;
  const int b  = widx >> 10;
  const int wl = widx & 1023;
  const int wh = wl >> 5, ww = wl & 31;

  // ---- phase 1: gather + LN -> bf16 token tile (row-swizzled) ----
  {
    const int lane16 = tid & 15;
    const float4 g4 = *(const float4*)(n1g + lane16 * 4);
    const float4 b4 = *(const float4*)(n1b + lane16 * 4);
    #pragma unroll
    for (int ps = 0; ps < 8; ++ps) {
      int t  = ps * 16 + (tid >> 4);
      int g  = t & 63;
      const float* src = ((t & 64) ? y : x)
          + ((long long)b * LL + (long long)(wh * GG + (g >> 3)) * W0c + (ww * GG + (g & 7))) * CC
          + lane16 * 4;
      float4 v = *(const float4*)src;
      float s  = v.x + v.y + v.z + v.w;
      float s2 = v.x * v.x + v.y * v.y + v.z * v.z + v.w * v.w;
      #pragma unroll
      for (int m = 1; m < 16; m <<= 1) { s += __shfl_xor(s, m); s2 += __shfl_xor(s2, m); }
      float mu  = s * (1.0f / 64.0f);
      float var = fmaxf(s2 * (1.0f / 64.0f) - mu * mu, 0.0f);
      float rs  = rsqrtf(var + 1e-5f);
      bf16x4 w4 = mk4_bf16((v.x - mu) * rs * g4.x + b4.x,
                           (v.y - mu) * rs * g4.y + b4.y,
                           (v.z - mu) * rs * g4.z + b4.z,
                           (v.w - mu) * rs * g4.w + b4.w);
      *(bf16x4*)(TOK_ + ((t * 128 + lane16 * 8) ^ ((t & 7) << 4))) = w4;
    }
  }
  __syncthreads();

  // ---- phase 2: QKV. waves 0,1 -> Q^T (32 ch each); waves 2,3 -> K^T;
  //      every wave also one 16-ch V tile. One TOK read feeds both. ----
  {
    bf16x8 awq[2][2];                   // A-frags of W^T (Q or K half)
    #pragma unroll
    for (int ct = 0; ct < 2; ++ct)
      #pragma unroll
      for (int ks = 0; ks < 2; ++ks)
        awq[ct][ks] = *(const bf16x8*)((const char*)wqkvF + ((((2 * wv + ct) * 2 + ks)) << 10) + l * 16);
    bf16x8 bwv[2];                      // B-frags of W_v tile
    #pragma unroll
    for (int ks = 0; ks < 2; ++ks)
      bwv[ks] = *(const bf16x8*)((const char*)wqkvF + (((8 + wv) * 2 + ks) << 10) + l * 16);

    f32x4 bq[2];
    #pragma unroll
    for (int ct = 0; ct < 2; ++ct) {
      f32x4 bb = *(const f32x4*)(qkv_b + (2 * wv + ct) * 16 + lg * 4);
      if (wv < 2) {
        const float qs = 0.25f * INV_LN2;
        bb[0] *= qs; bb[1] *= qs; bb[2] *= qs; bb[3] *= qs;
      }
      bq[ct] = bb;
    }
    const float bv = qkv_b[128 + wv * 16 + l15];
    char* const QKbuf = (wv < 2) ? QB_ : KB_;
    const int chv = wv * 16 + l15;        // V d-row in VT
    const int vswz = (chv & 7) << 4;

    #pragma unroll
    for (int nt = 0; nt < 8; ++nt) {
      const int row = 16 * nt + l15;
      const int rswz = (row & 7) << 4;
      bf16x8 t0 = *(const bf16x8*)(TOK_ + ((row * 128 +  0 + lg * 16) ^ rswz));
      bf16x8 t1 = *(const bf16x8*)(TOK_ + ((row * 128 + 64 + lg * 16) ^ rswz));
      // Q^T / K^T: D col=token(l15), row=4 consecutive d
      #pragma unroll
      for (int ct = 0; ct < 2; ++ct) {
        f32x4 a = bq[ct];
        a = __builtin_amdgcn_mfma_f32_16x16x32_bf16(awq[ct][0], t0, a, 0, 0, 0);
        a = __builtin_amdgcn_mfma_f32_16x16x32_bf16(awq[ct][1], t1, a, 0, 0, 0);
        int chL = (((2 * wv + ct) * 16) & 63) + lg * 4;
        *(bf16x4*)(QKbuf + ((row * 128 + chL * 2) ^ rswz)) = mk4_bf16(a[0], a[1], a[2], a[3]);
      }
      // V: D col=d(l15), row=4 consecutive tokens -> VT row write
      {
        f32x4 a = {bv, bv, bv, bv};
        a = __builtin_amdgcn_mfma_f32_16x16x32_bf16(t0, bwv[0], a, 0, 0, 0);
        a = __builtin_amdgcn_mfma_f32_16x16x32_bf16(t1, bwv[1], a, 0, 0, 0);
        int tok0 = 16 * nt + lg * 4;
        *(bf16x4*)(VT_ + ((chv * 256 + tok0 * 2) ^ vswz)) = mk4_bf16(a[0], a[1], a[2], a[3]);
      }
    }
  }
  __syncthreads();

  // ---- phase 3: attention, wave = head.  S^T = K x Q (swapped). ----
  {
    const int h = wv;
    const float* biasH = bias_exp + h * 16384;
    bf16x8 kf[8];
    #pragma unroll
    for (int kt = 0; kt < 8; ++kt) {
      bf16x8 f = {0, 0, 0, 0, 0, 0, 0, 0};
      if (l < 32) {
        int row = 16 * kt + l15;
        f = *(const bf16x8*)(KB_ + ((row * 128 + h * 32 + lg * 16) ^ ((row & 7) << 4)));
      }
      kf[kt] = f;
    }
    bf16x8 vf[4];                       // VT rows h*16+l15 (A-frag: row=d, k=tok)
    #pragma unroll
    for (int ks = 0; ks < 4; ++ks) {
      int row = h * 16 + l15;
      vf[ks] = *(const bf16x8*)(VT_ + ((row * 256 + ks * 64 + lg * 16) ^ ((row & 7) << 4)));
    }
    char* const PBw = PB_ + wv * 4096;
    const int pswz = (l15 & 7) << 4;

    // 2-stage pipeline: bias (global) + qf (LDS) prefetched one qt ahead.
    f32x4 biasE[8], biasO[8];
    bf16x8 qfE, qfO;
    ATT_LOADB(biasE, 0);
    ATT_LOADQ(qfE, 0);
    #pragma unroll
    for (int qq = 0; qq < 4; ++qq) {
      ATT_LOADB(biasO, 2 * qq + 1);
      ATT_LOADQ(qfO, 2 * qq + 1);
      ATT_BODY(2 * qq, biasE, qfE);
      if (qq < 3) {
        ATT_LOADB(biasE, 2 * qq + 2);
        ATT_LOADQ(qfE, 2 * qq + 2);
      }
      ATT_BODY(2 * qq + 1, biasO, qfO);
    }
  }
  __syncthreads();

  // ---- phase 4: proj^T (A = proj_w^T image, B = attn-out) + residual ----
  {
    bf16x8 pa2[2];
    #pragma unroll
    for (int ks = 0; ks < 2; ++ks)
      pa2[ks] = *(const bf16x8*)((const char*)projF + (((wv * 2 + ks)) << 10) + l * 16);
    const f32x4 bp = *(const f32x4*)(proj_b + wv * 16 + lg * 4);
    #pragma unroll
    for (int nt = 0; nt < 8; ++nt) {
      const int row = 16 * nt + l15;       // token
      const int rswz = (row & 7) << 4;
      bf16x8 t0 = *(const bf16x8*)(TOK_ + ((row * 128 +  0 + lg * 16) ^ rswz));
      bf16x8 t1 = *(const bf16x8*)(TOK_ + ((row * 128 + 64 + lg * 16) ^ rswz));
      f32x4 acc = bp;
      acc = __builtin_amdgcn_mfma_f32_16x16x32_bf16(pa2[0], t0, acc, 0, 0, 0);
      acc = __builtin_amdgcn_mfma_f32_16x16x32_bf16(pa2[1], t1, acc, 0, 0, 0);
      // D col=token(l15), row=4 consecutive out-ch -> dwordx4 residual
      int g = row & 63;
      long long base = ((long long)b * LL + (long long)(wh * GG + (g >> 3)) * W0c + (ww * GG + (g & 7))) * CC
                       + wv * 16 + lg * 4;
      const float* src = ((row & 64) ? y : x) + base;
      float* dst = out + ((row & 64) ? MODSZ : 0) + base;
      f32x4 sv = *(const f32x4*)src;
      sv[0] += acc[0]; sv[1] += acc[1]; sv[2] += acc[2]; sv[3] += acc[3];
      *(f32x4*)dst = sv;
    }
  }
}

// ---------------------------------------------------------------------------
// Kernel M v2: transposed-operand MFMA MLP (unchanged from round 8)
// ---------------------------------------------------------------------------
__launch_bounds__(256, 3)
__global__ void mlp_mfma_kernel(const float* __restrict__ n2g, const float* __restrict__ n2b,
                                const float* __restrict__ fx1b, const float* __restrict__ fx2b,
                                const float* __restrict__ fy1b, const float* __restrict__ fy2b,
                                const short* __restrict__ mlpW, float* __restrict__ out) {
  __shared__ __align__(16) char AR4[4][8192];

  const int tid = threadIdx.x;
  const int l   = tid & 63;
  const int l15 = l & 15;
  const int lg  = l >> 4;
  const int wv  = tid >> 6;
  const int bid = blockIdx.x;
  const int mod = bid >> 10;                         // 0=x, 1=y
  const long long wtok0 = (long long)(bid & 1023) * 128 + wv * 32;

  const float* b1 = mod ? fy1b : fx1b;
  const float* b2 = mod ? fy2b : fx2b;
  const short* w1T = mlpW + mod * 16384;
  const short* w2T = mlpW + 32768 + mod * 16384;
  float* const outm = out + (long long)mod * MODSZ;

  char* const TOKw = AR4[wv];            // 32 rows, stride 144 B
  char* const HBw  = AR4[wv] + 4608;     // 32 rows, stride 80 B

  {
    const f32x4 g4 = *(const f32x4*)(n2g + l15 * 4);
    const f32x4 b4 = *(const f32x4*)(n2b + l15 * 4);
    #pragma unroll
    for (int ps = 0; ps < 8; ++ps) {
      int t = ps * 4 + lg;
      const float* rp = outm + (wtok0 + t) * CC + l15 * 4;
      f32x4 v = *(const f32x4*)rp;
      float s  = v[0] + v[1] + v[2] + v[3];
      float s2 = v[0] * v[0] + v[1] * v[1] + v[2] * v[2] + v[3] * v[3];
      #pragma unroll
      for (int m = 1; m < 16; m <<= 1) { s += __shfl_xor(s, m); s2 += __shfl_xor(s2, m); }
      float mu  = s * (1.0f / 64.0f);
      float var = fmaxf(s2 * (1.0f / 64.0f) - mu * mu, 0.0f);
      float rs  = rsqrtf(var + 1e-5f);
      bf16x4 w4 = mk4_bf16((v[0] - mu) * rs * g4[0] + b4[0],
                           (v[1] - mu) * rs * g4[1] + b4[1],
                           (v[2] - mu) * rs * g4[2] + b4[2],
                           (v[3] - mu) * rs * g4[3] + b4[3]);
      *(bf16x4*)(TOKw + t * 144 + l15 * 8) = w4;
    }
  }

  bf16x8 tokB[2][2];
  #pragma unroll
  for (int ct = 0; ct < 2; ++ct)
    #pragma unroll
    for (int ks = 0; ks < 2; ++ks)
      tokB[ct][ks] = *(const bf16x8*)(TOKw + (16 * ct + l15) * 144 + ks * 64 + lg * 16);

  f32x4 acc2[4][2];
  #pragma unroll
  for (int n = 0; n < 4; ++n) {
    f32x4 bb = *(const f32x4*)(b2 + n * 16 + lg * 4);
    acc2[n][0] = bb; acc2[n][1] = bb;
  }

  #pragma unroll 1
  for (int g2 = 0; g2 < 8; ++g2) {
    #pragma unroll
    for (int sub = 0; sub < 2; ++sub) {
      const int nt = g2 * 2 + sub;
      bf16x8 wa0 = *(const bf16x8*)(w1T + ((nt * 2 + 0) << 9) + l * 8);
      bf16x8 wa1 = *(const bf16x8*)(w1T + ((nt * 2 + 1) << 9) + l * 8);
      f32x4 z = {0.0f, 0.0f, 0.0f, 0.0f};
      f32x4 d0 = __builtin_amdgcn_mfma_f32_16x16x32_bf16(wa0, tokB[0][0], z, 0, 0, 0);
      d0 = __builtin_amdgcn_mfma_f32_16x16x32_bf16(wa1, tokB[0][1], d0, 0, 0, 0);
      f32x4 d1 = __builtin_amdgcn_mfma_f32_16x16x32_bf16(wa0, tokB[1][0], z, 0, 0, 0);
      d1 = __builtin_amdgcn_mfma_f32_16x16x32_bf16(wa1, tokB[1][1], d1, 0, 0, 0);
      f32x4 b1v = *(const f32x4*)(b1 + nt * 16 + lg * 4);
      bf16x4 h0 = mk4_bf16(gelu_tanh(d0[0] + b1v[0]), gelu_tanh(d0[1] + b1v[1]),
                           gelu_tanh(d0[2] + b1v[2]), gelu_tanh(d0[3] + b1v[3]));
      bf16x4 h1 = mk4_bf16(gelu_tanh(d1[0] + b1v[0]), gelu_tanh(d1[1] + b1v[1]),
                           gelu_tanh(d1[2] + b1v[2]), gelu_tanh(d1[3] + b1v[3]));
      *(bf16x4*)(HBw + l15 * 80        + sub * 32 + lg * 8) = h0;
      *(bf16x4*)(HBw + (16 + l15) * 80 + sub * 32 + lg * 8) = h1;
    }
    bf16x8 hb0 = *(const bf16x8*)(HBw + l15 * 80        + lg * 16);
    bf16x8 hb1 = *(const bf16x8*)(HBw + (16 + l15) * 80 + lg * 16);
    #pragma unroll
    for (int n = 0; n < 4; ++n) {
      bf16x8 wa = *(const bf16x8*)(w2T + ((n * 8 + g2) << 9) + l * 8);
      acc2[n][0] = __builtin_amdgcn_mfma_f32_16x16x32_bf16(wa, hb0, acc2[n][0], 0, 0, 0);
      acc2[n][1] = __builtin_amdgcn_mfma_f32_16x16x32_bf16(wa, hb1, acc2[n][1], 0, 0, 0);
    }
  }

  #pragma unroll
  for (int n = 0; n < 4; ++n)
    #pragma unroll
    for (int ct = 0; ct < 2; ++ct) {
      float* rp = outm + (wtok0 + 16 * ct + l15) * CC + n * 16 + lg * 4;
      f32x4 o = *(const f32x4*)rp;
      o[0] += acc2[n][ct][0]; o[1] += acc2[n][ct][1];
      o[2] += acc2[n][ct][2]; o[3] += acc2[n][ct][3];
      *(f32x4*)rp = o;
    }
}

// ---------------------------------------------------------------------------
extern "C" void kernel_launch(void* const* d_in, const int* in_sizes, int n_in,
                              void* d_out, int out_size, void* d_ws, size_t ws_size,
                              hipStream_t stream) {
  const float* x      = (const float*)d_in[0];
  const float* y      = (const float*)d_in[1];
  const float* n1g    = (const float*)d_in[2];
  const float* n1b    = (const float*)d_in[3];
  const float* qkv_w  = (const float*)d_in[4];
  const float* qkv_b  = (const float*)d_in[5];
  const float* proj_w = (const float*)d_in[6];
  const float* proj_b = (const float*)d_in[7];
  const float* pp_w   = (const float*)d_in[8];
  const float* pp_b   = (const float*)d_in[9];
  const float* ln1g   = (const float*)d_in[10];
  const float* ln1b   = (const float*)d_in[11];
  const float* l1w    = (const float*)d_in[12];
  const float* l1b    = (const float*)d_in[13];
  const float* ln2g   = (const float*)d_in[14];
  const float* ln2b   = (const float*)d_in[15];
  const float* l2w    = (const float*)d_in[16];
  const float* l2b    = (const float*)d_in[17];
  const float* ln3g   = (const float*)d_in[18];
  const float* ln3b   = (const float*)d_in[19];
  const float* l3w    = (const float*)d_in[20];
  const float* l3b    = (const float*)d_in[21];
  const float* n2g    = (const float*)d_in[22];
  const float* n2b    = (const float*)d_in[23];
  const float* fx1w   = (const float*)d_in[24];
  const float* fx1b   = (const float*)d_in[25];
  const float* fx2w   = (const float*)d_in[26];
  const float* fx2b   = (const float*)d_in[27];
  const float* fy1w   = (const float*)d_in[28];
  const float* fy1b   = (const float*)d_in[29];
  const float* fy2w   = (const float*)d_in[30];
  const float* fy2b   = (const float*)d_in[31];
  (void)in_sizes; (void)n_in; (void)out_size; (void)ws_size;

  float* out = (float*)d_out;
  char*  ws  = (char*)d_ws;
  float* p_table  = (float*)(ws + WS_PTAB);
  float* bias_exp = (float*)(ws + WS_BIAS);
  short* wqkvF    = (short*)(ws + WS_WQKV);
  short* projF    = (short*)(ws + WS_WPROJ);
  short* mlpW     = (short*)(ws + WS_MLPW);

  pbias_kernel<<<1, 512, 0, stream>>>(pp_w, pp_b, ln1g, ln1b, l1w, l1b,
                                      ln2g, ln2b, l2w, l2b, ln3g, ln3b, l3w, l3b, p_table);
  bias_expand_kernel<<<64, 256, 0, stream>>>(p_table, bias_exp);
  prep_w_kernel<<<64, 256, 0, stream>>>(qkv_w, proj_w, wqkvF, projF);
  prep_mlp_w_kernel<<<256, 256, 0, stream>>>(fx1w, fy1w, fx2w, fy2w, mlpW);
  win_attn_kernel<<<NWIN, 256, 0, stream>>>(x, y, n1g, n1b, qkv_b, proj_b,
                                            bias_exp, wqkvF, projF, out);
  mlp_mfma_kernel<<<2048, 256, 0, stream>>>(n2g, n2b, fx1b, fx2b, fy1b, fy2b,
                                            mlpW, out);
}